// Round 4
// baseline (515.351 us; speedup 1.0000x reference)
//
#include <hip/hip_runtime.h>
#include <math.h>

namespace {

typedef float f32x4 __attribute__((ext_vector_type(4)));
typedef float f32x16 __attribute__((ext_vector_type(16)));
typedef short bf16x8 __attribute__((ext_vector_type(8)));
typedef unsigned short ushort_t;

constexpr int B  = 1024;
constexpr int M  = 65536;
constexpr int D  = 384;
constexpr int H  = 384;
constexpr int KK = 5;
constexpr int NC = 128;         // chunks over M
constexpr int CHUNK = M / NC;   // 512 mems per chunk
constexpr float FEPS = 1e-8f;

__device__ __forceinline__ ushort_t f2bf(float x) {
  unsigned int u = __float_as_uint(x);
  unsigned int r = (u + 0x7FFFu + ((u >> 16) & 1u)) >> 16;   // RNE
  return (ushort_t)r;
}
__device__ __forceinline__ float bf2f(ushort_t h) {
  return __uint_as_float(((unsigned int)h) << 16);
}

__device__ __forceinline__ void async16(const ushort_t* g, ushort_t* l) {
  __builtin_amdgcn_global_load_lds(
      (const __attribute__((address_space(1))) unsigned int*)g,
      (__attribute__((address_space(3))) unsigned int*)l, 16, 0, 0);
}

__device__ __forceinline__ void insert3b(unsigned int* k, unsigned int v) {
  unsigned int t0 = min(k[0], v); k[0] = max(k[0], v);
  unsigned int t1 = min(k[1], t0); k[1] = max(k[1], t0);
  k[2] = max(k[2], t1);
}
__device__ __forceinline__ void insert5b(unsigned int* k, unsigned int v) {
  unsigned int t0 = min(k[0], v); k[0] = max(k[0], v);
  unsigned int t1 = min(k[1], t0); k[1] = max(k[1], t0);
  unsigned int t2 = min(k[2], t1); k[2] = max(k[2], t1);
  unsigned int t3 = min(k[3], t2); k[3] = max(k[3], t2);
  k[4] = max(k[4], t3);
}

// ================= mega prep: mem split+stats | q splits | weight splits ====
__global__ __launch_bounds__(256) void k_prep(
    const float* __restrict__ q, const float* __restrict__ mem,
    const float* __restrict__ coords, const float* __restrict__ sw,
    const float* __restrict__ W_ih, const float* __restrict__ W_hh,
    const float* __restrict__ W_g,
    ushort_t* __restrict__ qh, ushort_t* __restrict__ qrh, ushort_t* __restrict__ qrl,
    ushort_t* __restrict__ mh, ushort_t* __restrict__ ml,
    float2* __restrict__ f2a, float2* __restrict__ f2b,
    ushort_t* __restrict__ wihh, ushort_t* __restrict__ wihl,
    ushort_t* __restrict__ whhh, ushort_t* __restrict__ whhl,
    ushort_t* __restrict__ wgh, ushort_t* __restrict__ wgl) {
  int wv = threadIdx.x >> 6, lane = threadIdx.x & 63;
  int bid = blockIdx.x;
  if (bid < M/4) {
    int r = bid*4 + wv;
    float cx = 0.f, cy = 0.f;
    for (int i = lane; i < H; i += 64) { cx += sw[2*i]; cy += sw[2*i+1]; }
#pragma unroll
    for (int o = 32; o > 0; o >>= 1) { cx += __shfl_xor(cx, o); cy += __shfl_xor(cy, o); }
    cx *= (1.0f/384.0f); cy *= (1.0f/384.0f);
    float x[6]; float s = 0.f;
#pragma unroll
    for (int k = 0; k < 6; ++k) { x[k] = mem[(size_t)r*D + lane + 64*k]; s += x[k]*x[k]; }
#pragma unroll
    for (int o = 32; o > 0; o >>= 1) s += __shfl_xor(s, o);
#pragma unroll
    for (int k = 0; k < 6; ++k) {
      ushort_t h = f2bf(x[k]);
      mh[(size_t)r*D + lane + 64*k] = h;
      ml[(size_t)r*D + lane + 64*k] = f2bf(x[k] - bf2f(h));
    }
    if (lane == 0) {
      float mn = sqrtf(s);
      float dx = coords[2*r] - cx, dy = coords[2*r+1] - cy;
      float act = 1.0f / (1.0f + sqrtf(dx*dx + dy*dy));
      f2a[r] = make_float2(1.0f / mn, act + 2.0f);
      f2b[r] = make_float2(mn, act);
    }
  } else if (bid < M/4 + B/4) {
    int r = (bid - M/4)*4 + wv;
    float x[6]; float s = 0.f;
#pragma unroll
    for (int k = 0; k < 6; ++k) { x[k] = q[(size_t)r*D + lane + 64*k]; s += x[k]*x[k]; }
#pragma unroll
    for (int o = 32; o > 0; o >>= 1) s += __shfl_xor(s, o);
    float inv = 1.0f / sqrtf(s);
#pragma unroll
    for (int k = 0; k < 6; ++k) {
      ushort_t rh = f2bf(x[k]);
      qrh[(size_t)r*D + lane + 64*k] = rh;
      qrl[(size_t)r*D + lane + 64*k] = f2bf(x[k] - bf2f(rh));
      qh [(size_t)r*D + lane + 64*k] = f2bf(x[k] * inv);
    }
  } else {
    int r = (bid - M/4 - B/4)*4 + wv;   // 0..1151
    const float* src; ushort_t* dh; ushort_t* dl;
    if (r < 384)      { src = W_ih + (size_t)r*D;       dh = wihh + (size_t)r*D;       dl = wihl + (size_t)r*D; }
    else if (r < 768) { src = W_hh + (size_t)(r-384)*D; dh = whhh + (size_t)(r-384)*D; dl = whhl + (size_t)(r-384)*D; }
    else              { src = W_g  + (size_t)(r-768)*D; dh = wgh  + (size_t)(r-768)*D; dl = wgl  + (size_t)(r-768)*D; }
#pragma unroll
    for (int k = 0; k < 6; ++k) {
      float v = src[lane + 64*k];
      ushort_t h = f2bf(v);
      dh[lane + 64*k] = h;
      dl[lane + 64*k] = f2bf(v - bf2f(h));
    }
  }
}

// ========== sim: 2-term split-bf16 32x32x16 MFMA + per-lane top-3 ==========
// grid (B/128=8, NC=128), 256 threads = 4 waves (2x2), wave tile 64m x 64q
__global__ __launch_bounds__(256, 2) void k_sim(
    const ushort_t* __restrict__ qh,
    const ushort_t* __restrict__ mh, const ushort_t* __restrict__ ml,
    const float2* __restrict__ f2a, unsigned int* __restrict__ keybuf) {
  __shared__ __align__(16) ushort_t sQh[128*32];
  __shared__ __align__(16) ushort_t sMh[128*32];
  __shared__ __align__(16) ushort_t sMl[128*32];

  const int tid = threadIdx.x, lane = tid & 63, wave = tid >> 6;
  const int wr = wave >> 1, wc = wave & 1;
  const int l31 = lane & 31, half = lane >> 5;
  const int qb = blockIdx.x, nc = blockIdx.y;
  const int rowoff = lane >> 2, koff = (lane & 3) * 8;
  const size_t qrow0 = (size_t)qb * 128;

  unsigned int keys[2][3];
#pragma unroll
  for (int j = 0; j < 2; ++j) { keys[j][0] = 0; keys[j][1] = 0; keys[j][2] = 0; }

  for (int mt = 0; mt < 4; ++mt) {
    const size_t mrow0 = (size_t)nc * CHUNK + (size_t)mt * 128;
    f32x16 acc[2][2];
#pragma unroll
    for (int i = 0; i < 2; ++i)
#pragma unroll
      for (int j = 0; j < 2; ++j) acc[i][j] = (f32x16)0.0f;

    for (int kt = 0; kt < D; kt += 32) {
      __syncthreads();
#pragma unroll
      for (int n = 0; n < 6; ++n) {
        int f = wave*6 + n; int arr = f >> 3, slot = f & 7;
        const ushort_t* src = arr == 0 ? qh : (arr == 1 ? mh : ml);
        ushort_t* dst = arr == 0 ? sQh : (arr == 1 ? sMh : sMl);
        size_t rowb = arr == 0 ? qrow0 : mrow0;
        async16(src + (rowb + slot*16 + rowoff)*D + kt + koff,
                dst + slot*512 + lane*8);
      }
      __syncthreads();

      bf16x8 ah[2][2], al[2][2], bh[2][2];
#pragma unroll
      for (int i = 0; i < 2; ++i)
#pragma unroll
        for (int s = 0; s < 2; ++s) {
          int ro = (wr*64 + i*32 + l31)*32 + s*16 + half*8;
          ah[i][s] = *(const bf16x8*)&sMh[ro];
          al[i][s] = *(const bf16x8*)&sMl[ro];
          int co = (wc*64 + i*32 + l31)*32 + s*16 + half*8;
          bh[i][s] = *(const bf16x8*)&sQh[co];
        }
#pragma unroll
      for (int i = 0; i < 2; ++i)
#pragma unroll
        for (int j = 0; j < 2; ++j)
#pragma unroll
          for (int s = 0; s < 2; ++s) {
            acc[i][j] = __builtin_amdgcn_mfma_f32_32x32x16_bf16(ah[i][s], bh[j][s], acc[i][j], 0, 0, 0);
            acc[i][j] = __builtin_amdgcn_mfma_f32_32x32x16_bf16(al[i][s], bh[j][s], acc[i][j], 0, 0, 0);
          }
    }

    // epilogue: C layout col=lane&31, row=(r&3)+8*(r>>2)+4*half
#pragma unroll
    for (int i = 0; i < 2; ++i)
#pragma unroll
      for (int rg = 0; rg < 4; ++rg)
#pragma unroll
        for (int rr = 0; rr < 4; ++rr) {
          int rl = wr*64 + i*32 + half*4 + rr + 8*rg;
          float2 fa = f2a[mrow0 + rl];
          unsigned int idx = (unsigned int)(((nc & 1) << 9) | (mt*128 + rl));
          float v0 = fmaf(acc[i][0][rg*4+rr], fa.x, fa.y);
          insert3b(keys[0], (__float_as_uint(v0) & 0xFFFFFC00u) | idx);
          float v1 = fmaf(acc[i][1][rg*4+rr], fa.x, fa.y);
          insert3b(keys[1], (__float_as_uint(v1) & 0xFFFFFC00u) | idx);
        }
  }

#pragma unroll
  for (int j = 0; j < 2; ++j) {
    int q_local = wc*64 + j*32 + l31;
    int c = wr*2 + half;
    size_t off = ((size_t)(qb*128 + q_local) * NC + nc) * 12 + c*3;
    keybuf[off+0] = keys[j][0];
    keybuf[off+1] = keys[j][1];
    keybuf[off+2] = keys[j][2];
  }
}

// ============ merge candidates + exact fp32 rescore; wave per query =========
__global__ void k_merge(const unsigned int* __restrict__ keybuf,
                        const float* __restrict__ query, const float* __restrict__ memv,
                        const float2* __restrict__ f2b, int* __restrict__ topk) {
  int lane = threadIdx.x & 63, w = threadIdx.x >> 6;
  int q = blockIdx.x * 4 + w;

  // lane covers chunks 2*lane, 2*lane+1: 24 contiguous keys
  const unsigned int* kb = keybuf + (size_t)q * (NC*12) + (size_t)lane * 24;
  unsigned int k5[5] = {0,0,0,0,0};
#pragma unroll
  for (int c = 0; c < 6; ++c) {
    uint4 v = *(const uint4*)(kb + c*4);
    insert5b(k5, v.x); insert5b(k5, v.y); insert5b(k5, v.z); insert5b(k5, v.w);
  }

  int cand[16];
#pragma unroll
  for (int p = 0; p < 16; ++p) {
    unsigned int bk = k5[0]; int blv = lane;
#pragma unroll
    for (int off = 1; off < 64; off <<= 1) {
      unsigned int ok = (unsigned int)__shfl_xor((int)bk, off);
      int ol = __shfl_xor(blv, off);
      if (ok > bk || (ok == bk && ol < blv)) { bk = ok; blv = ol; }
    }
    cand[p] = (blv << 10) | (int)(bk & 1023u);
    if (lane == blv) { k5[0]=k5[1]; k5[1]=k5[2]; k5[2]=k5[3]; k5[3]=k5[4]; k5[4]=0; }
  }

  float qv[6]; float sq = 0.f;
#pragma unroll
  for (int k = 0; k < 6; ++k) { qv[k] = query[(size_t)q*D + lane + 64*k]; sq += qv[k]*qv[k]; }
#pragma unroll
  for (int o = 32; o > 0; o >>= 1) sq += __shfl_xor(sq, o);
  float qn = sqrtf(sq);

  float simv[16]; int simi[16];
#pragma unroll
  for (int p = 0; p < 16; ++p) {
    int mi = cand[p];
    float d = 0.f;
#pragma unroll
    for (int k = 0; k < 6; ++k) d += qv[k] * memv[(size_t)mi*D + lane + 64*k];
#pragma unroll
    for (int o = 32; o > 0; o >>= 1) d += __shfl_xor(d, o);
    float2 fb = f2b[mi];
    simv[p] = d / fmaxf(qn * fb.x, FEPS) + fb.y;
    simi[p] = mi;
  }
  if (lane == 0) {
    for (int s = 0; s < KK; ++s) {
      int best = -1; float bv = -1e30f; int bi = 0x7FFFFFFF;
      for (int p = 0; p < 16; ++p) {
        if (simi[p] < 0) continue;
        if (simv[p] > bv || (simv[p] == bv && simi[p] < bi)) { best = p; bv = simv[p]; bi = simi[p]; }
      }
      topk[q*KK + s] = simi[best];
      simi[best] = -1;
    }
  }
}

// ===== tail1: x_proj (gathered, 96 row-tiles) + gate (16 row-tiles) ====
// grid (112, 6); 64x64 tile, K=384 in 3 rounds of 4x32 subtiles; 3-term split
__global__ __launch_bounds__(256) void k_tail1(
    const ushort_t* __restrict__ qrh, const ushort_t* __restrict__ qrl,
    const ushort_t* __restrict__ mh, const ushort_t* __restrict__ ml,
    const int* __restrict__ topk,
    const ushort_t* __restrict__ wihh, const ushort_t* __restrict__ wihl,
    const ushort_t* __restrict__ wgh, const ushort_t* __restrict__ wgl,
    const float* __restrict__ b_ih, const float* __restrict__ b_g,
    float* __restrict__ xp, float* __restrict__ gate) {
  __shared__ __align__(16) ushort_t sAh[64*128];
  __shared__ __align__(16) ushort_t sAl[64*128];
  __shared__ __align__(16) ushort_t sWh[64*128];
  __shared__ __align__(16) ushort_t sWl[64*128];

  const int tid = threadIdx.x, lane = tid & 63, wave = tid >> 6;
  const int wr = wave >> 1, wc = wave & 1;
  const int t = lane & 15, quad = lane >> 4;
  const bool xmode = blockIdx.x < 96;
  const int cbase = blockIdx.y * 64;
  const int rowoff = lane >> 2, koff = (lane & 3) * 8;

  const ushort_t* gp[4];
  if (wave < 2) {
#pragma unroll
    for (int slot = 0; slot < 4; ++slot) {
      int rl = slot*16 + rowoff;
      const ushort_t* src;
      if (xmode) {
        int g = blockIdx.x*64 + rl;
        int b = g / 6, tt = g - b*6;
        if (tt == 0) src = (wave == 0 ? qrh : qrl) + (size_t)b * D;
        else         src = (wave == 0 ? mh  : ml ) + (size_t)topk[b*KK + tt - 1] * D;
      } else {
        int rq = (blockIdx.x - 96)*64 + rl;
        src = (wave == 0 ? qrh : qrl) + (size_t)rq * D;
      }
      gp[slot] = src + koff;
    }
  } else {
#pragma unroll
    for (int slot = 0; slot < 4; ++slot) {
      int rl = slot*16 + rowoff;
      const ushort_t* wsrc = xmode ? (wave == 2 ? wihh : wihl)
                                   : (wave == 2 ? wgh  : wgl);
      gp[slot] = wsrc + (size_t)(cbase + rl) * D + koff;
    }
  }
  ushort_t* ldst = (wave == 0) ? sAh : (wave == 1) ? sAl : (wave == 2) ? sWh : sWl;

  f32x4 acc[2][2];
#pragma unroll
  for (int i = 0; i < 2; ++i)
#pragma unroll
    for (int j = 0; j < 2; ++j) acc[i][j] = (f32x4)0.0f;

  for (int r3 = 0; r3 < 3; ++r3) {
    __syncthreads();
#pragma unroll
    for (int s = 0; s < 4; ++s)
#pragma unroll
      for (int slot = 0; slot < 4; ++slot)
        async16(gp[slot] + r3*128 + s*32, ldst + s*2048 + slot*512 + lane*8);
    __syncthreads();
#pragma unroll
    for (int s = 0; s < 4; ++s) {
      bf16x8 ah[2], al[2], bh[2], bl[2];
#pragma unroll
      for (int i = 0; i < 2; ++i) {
        int ro = s*2048 + (wr*32 + i*16 + t)*32 + quad*8;
        ah[i] = *(const bf16x8*)&sAh[ro];
        al[i] = *(const bf16x8*)&sAl[ro];
        int co = s*2048 + (wc*32 + i*16 + t)*32 + quad*8;
        bh[i] = *(const bf16x8*)&sWh[co];
        bl[i] = *(const bf16x8*)&sWl[co];
      }
#pragma unroll
      for (int i = 0; i < 2; ++i)
#pragma unroll
        for (int j = 0; j < 2; ++j) {
          acc[i][j] = __builtin_amdgcn_mfma_f32_16x16x32_bf16(ah[i], bh[j], acc[i][j], 0, 0, 0);
          acc[i][j] = __builtin_amdgcn_mfma_f32_16x16x32_bf16(ah[i], bl[j], acc[i][j], 0, 0, 0);
          acc[i][j] = __builtin_amdgcn_mfma_f32_16x16x32_bf16(al[i], bh[j], acc[i][j], 0, 0, 0);
        }
    }
  }

#pragma unroll
  for (int i = 0; i < 2; ++i)
#pragma unroll
    for (int j = 0; j < 2; ++j)
#pragma unroll
      for (int r = 0; r < 4; ++r) {
        int rloc = wr*32 + i*16 + quad*4 + r;
        int h = cbase + wc*32 + j*16 + t;
        float a = acc[i][j][r];
        if (xmode) {
          int g = blockIdx.x*64 + rloc;
          xp[(size_t)g*H + h] = a + b_ih[h];
        } else {
          int rq = (blockIdx.x - 96)*64 + rloc;
          gate[(size_t)rq*H + h] = 1.0f / (1.0f + expf(-(a + b_g[h])));
        }
      }
}

// ========== fused RNN: h1 + 5 recurrent steps + gated output blend =========
// grid 64 blocks x 256 thr; block owns 16 query rows; h in LDS (hi/lo);
// W_hh B-fragments read directly from global (L2-resident) - no staging.
__global__ __launch_bounds__(256) void k_rnn_all(
    const float* __restrict__ xp, const float* __restrict__ gate,
    const ushort_t* __restrict__ whhh, const ushort_t* __restrict__ whhl,
    const float* __restrict__ b_hh, float* __restrict__ out) {
  __shared__ __align__(16) ushort_t sHh[16*392];
  __shared__ __align__(16) ushort_t sHl[16*392];

  const int tid = threadIdx.x, lane = tid & 63, wave = tid >> 6;
  const int t16 = lane & 15, quad = lane >> 4;
  const int rbase = blockIdx.x * 16;
  const int ncol0 = wave * 96;

  // h1 = tanh(xp[:,0,:] + b_hh)
  {
    int row = tid >> 4, cw = tid & 15;
    size_t gb = (size_t)(rbase + row) * (6*H);
#pragma unroll
    for (int c = 0; c < 24; ++c) {
      int col = cw + 16*c;
      float hv = tanhf(xp[gb + col] + b_hh[col]);
      ushort_t hi = f2bf(hv);
      sHh[row*392 + col] = hi;
      sHl[row*392 + col] = f2bf(hv - bf2f(hi));
    }
  }
  __syncthreads();

  for (int t = 1; t <= 5; ++t) {
    f32x4 acc[6];
#pragma unroll
    for (int jj = 0; jj < 6; ++jj) acc[jj] = (f32x4)0.0f;

    for (int kt = 0; kt < D; kt += 32) {
      bf16x8 ah = *(const bf16x8*)&sHh[t16*392 + kt + quad*8];
      bf16x8 al = *(const bf16x8*)&sHl[t16*392 + kt + quad*8];
#pragma unroll
      for (int jj = 0; jj < 6; ++jj) {
        int n = ncol0 + jj*16 + t16;
        bf16x8 bh = *(const bf16x8*)(whhh + (size_t)n*D + kt + quad*8);
        bf16x8 bl = *(const bf16x8*)(whhl + (size_t)n*D + kt + quad*8);
        acc[jj] = __builtin_amdgcn_mfma_f32_16x16x32_bf16(ah, bh, acc[jj], 0, 0, 0);
        acc[jj] = __builtin_amdgcn_mfma_f32_16x16x32_bf16(ah, bl, acc[jj], 0, 0, 0);
        acc[jj] = __builtin_amdgcn_mfma_f32_16x16x32_bf16(al, bh, acc[jj], 0, 0, 0);
      }
    }
    __syncthreads();   // all LDS reads complete before overwrite

    if (t < 5) {
#pragma unroll
      for (int jj = 0; jj < 6; ++jj)
#pragma unroll
        for (int r = 0; r < 4; ++r) {
          int row = quad*4 + r;
          int col = ncol0 + jj*16 + t16;
          float v = acc[jj][r] + b_hh[col] + xp[(size_t)(rbase+row)*(6*H) + t*H + col];
          float hv = tanhf(v);
          ushort_t hi = f2bf(hv);
          sHh[row*392 + col] = hi;
          sHl[row*392 + col] = f2bf(hv - bf2f(hi));
        }
      __syncthreads();
    } else {
#pragma unroll
      for (int jj = 0; jj < 6; ++jj)
#pragma unroll
        for (int r = 0; r < 4; ++r) {
          int row = quad*4 + r;
          int col = ncol0 + jj*16 + t16;
          size_t gb = (size_t)(rbase+row);
          float v = acc[jj][r] + b_hh[col] + xp[gb*(6*H) + 5*H + col];
          float hv = tanhf(v);
          float g = gate[gb*H + col];
          out[gb*H + col] = g*hv + (1.0f - g)*xp[gb*(6*H) + col];
        }
    }
  }
}

} // namespace

extern "C" void kernel_launch(void* const* d_in, const int* in_sizes, int n_in,
                              void* d_out, int out_size, void* d_ws, size_t ws_size,
                              hipStream_t stream) {
  const float* query = (const float*)d_in[0];
  const float* memv  = (const float*)d_in[1];
  const float* coords= (const float*)d_in[2];
  const float* sw    = (const float*)d_in[3];
  const float* W_ih  = (const float*)d_in[4];
  const float* b_ih  = (const float*)d_in[5];
  const float* W_hh  = (const float*)d_in[6];
  const float* b_hh  = (const float*)d_in[7];
  const float* W_g   = (const float*)d_in[8];
  const float* b_g   = (const float*)d_in[9];
  float* out = (float*)d_out;

  char* p = (char*)d_ws;
  auto alloc = [&](size_t bytes) {
    char* r = p; p += (bytes + 255) & ~(size_t)255; return r;
  };
  ushort_t* qh  = (ushort_t*)alloc((size_t)B * D * 2);
  ushort_t* qrh = (ushort_t*)alloc((size_t)B * D * 2);
  ushort_t* qrl = (ushort_t*)alloc((size_t)B * D * 2);
  ushort_t* mh  = (ushort_t*)alloc((size_t)M * D * 2);
  ushort_t* ml  = (ushort_t*)alloc((size_t)M * D * 2);
  float2* f2a   = (float2*)alloc((size_t)M * 8);
  float2* f2b   = (float2*)alloc((size_t)M * 8);
  ushort_t* wihh = (ushort_t*)alloc((size_t)H * D * 2);
  ushort_t* wihl = (ushort_t*)alloc((size_t)H * D * 2);
  ushort_t* whhh = (ushort_t*)alloc((size_t)H * D * 2);
  ushort_t* whhl = (ushort_t*)alloc((size_t)H * D * 2);
  ushort_t* wgh  = (ushort_t*)alloc((size_t)H * D * 2);
  ushort_t* wgl  = (ushort_t*)alloc((size_t)H * D * 2);
  unsigned int* keybuf = (unsigned int*)alloc((size_t)B * NC * 12 * 4);
  int*   topk   = (int*)alloc((size_t)B * KK * 4);
  float* xp     = (float*)alloc((size_t)B * 6 * H * 4);
  float* gate   = (float*)alloc((size_t)B * H * 4);

  k_prep<<<M/4 + B/4 + 288, 256, 0, stream>>>(
      query, memv, coords, sw, W_ih, W_hh, W_g,
      qh, qrh, qrl, mh, ml, f2a, f2b,
      wihh, wihl, whhh, whhl, wgh, wgl);
  k_sim<<<dim3(B/128, NC), 256, 0, stream>>>(qh, mh, ml, f2a, keybuf);
  k_merge<<<B/4, 256, 0, stream>>>(keybuf, query, memv, f2b, topk);
  k_tail1<<<dim3(112, 6), 256, 0, stream>>>(
      qrh, qrl, mh, ml, topk, wihh, wihl, wgh, wgl,
      b_ih, b_g, xp, gate);
  k_rnn_all<<<64, 256, 0, stream>>>(xp, gate, whhh, whhl, b_hh, out);
}

// Round 5
// 448.775 us; speedup vs baseline: 1.1484x; 1.1484x over previous
//
#include <hip/hip_runtime.h>
#include <math.h>

namespace {

typedef float f32x4 __attribute__((ext_vector_type(4)));
typedef float f32x16 __attribute__((ext_vector_type(16)));
typedef short bf16x8 __attribute__((ext_vector_type(8)));
typedef unsigned short ushort_t;

constexpr int B  = 1024;
constexpr int M  = 65536;
constexpr int D  = 384;
constexpr int H  = 384;
constexpr int KK = 5;
constexpr int NC = 128;         // chunks over M
constexpr int CHUNK = M / NC;   // 512 mems per chunk
constexpr float FEPS = 1e-8f;

__device__ __forceinline__ ushort_t f2bf(float x) {
  unsigned int u = __float_as_uint(x);
  unsigned int r = (u + 0x7FFFu + ((u >> 16) & 1u)) >> 16;   // RNE
  return (ushort_t)r;
}
__device__ __forceinline__ float bf2f(ushort_t h) {
  return __uint_as_float(((unsigned int)h) << 16);
}

__device__ __forceinline__ void async16(const ushort_t* g, ushort_t* l) {
  __builtin_amdgcn_global_load_lds(
      (const __attribute__((address_space(1))) unsigned int*)g,
      (__attribute__((address_space(3))) unsigned int*)l, 16, 0, 0);
}

__device__ __forceinline__ void insert3b(unsigned int* k, unsigned int v) {
  unsigned int t0 = min(k[0], v); k[0] = max(k[0], v);
  unsigned int t1 = min(k[1], t0); k[1] = max(k[1], t0);
  k[2] = max(k[2], t1);
}
__device__ __forceinline__ void insert5b(unsigned int* k, unsigned int v) {
  unsigned int t0 = min(k[0], v); k[0] = max(k[0], v);
  unsigned int t1 = min(k[1], t0); k[1] = max(k[1], t0);
  unsigned int t2 = min(k[2], t1); k[2] = max(k[2], t1);
  unsigned int t3 = min(k[3], t2); k[3] = max(k[3], t2);
  k[4] = max(k[4], t3);
}

// swizzled per-lane global k-offset for staging: LDS granule (lane&3) of row
// (lane>>2) holds logical granule (lane&3) ^ ((row>>1)&3).  [bank-conflict fix]
__device__ __forceinline__ int swz_koff(int lane) {
  return (((lane & 3) ^ ((lane >> 3) & 3)) * 8);
}

// ================= mega prep: mem split+stats | q splits | weight splits ====
__global__ __launch_bounds__(256) void k_prep(
    const float* __restrict__ q, const float* __restrict__ mem,
    const float* __restrict__ coords, const float* __restrict__ sw,
    const float* __restrict__ W_ih, const float* __restrict__ W_hh,
    const float* __restrict__ W_g,
    ushort_t* __restrict__ qh, ushort_t* __restrict__ qrh, ushort_t* __restrict__ qrl,
    ushort_t* __restrict__ mh, ushort_t* __restrict__ ml,
    float2* __restrict__ f2a, float2* __restrict__ f2b,
    ushort_t* __restrict__ wihh, ushort_t* __restrict__ wihl,
    ushort_t* __restrict__ whhh, ushort_t* __restrict__ whhl,
    ushort_t* __restrict__ wgh, ushort_t* __restrict__ wgl) {
  int wv = threadIdx.x >> 6, lane = threadIdx.x & 63;
  int bid = blockIdx.x;
  if (bid < M/4) {
    int r = bid*4 + wv;
    float cx = 0.f, cy = 0.f;
    for (int i = lane; i < H; i += 64) { cx += sw[2*i]; cy += sw[2*i+1]; }
#pragma unroll
    for (int o = 32; o > 0; o >>= 1) { cx += __shfl_xor(cx, o); cy += __shfl_xor(cy, o); }
    cx *= (1.0f/384.0f); cy *= (1.0f/384.0f);
    float x[6]; float s = 0.f;
#pragma unroll
    for (int k = 0; k < 6; ++k) { x[k] = mem[(size_t)r*D + lane + 64*k]; s += x[k]*x[k]; }
#pragma unroll
    for (int o = 32; o > 0; o >>= 1) s += __shfl_xor(s, o);
#pragma unroll
    for (int k = 0; k < 6; ++k) {
      ushort_t h = f2bf(x[k]);
      mh[(size_t)r*D + lane + 64*k] = h;
      ml[(size_t)r*D + lane + 64*k] = f2bf(x[k] - bf2f(h));
    }
    if (lane == 0) {
      float mn = sqrtf(s);
      float dx = coords[2*r] - cx, dy = coords[2*r+1] - cy;
      float act = 1.0f / (1.0f + sqrtf(dx*dx + dy*dy));
      f2a[r] = make_float2(1.0f / mn, act + 2.0f);
      f2b[r] = make_float2(mn, act);
    }
  } else if (bid < M/4 + B/4) {
    int r = (bid - M/4)*4 + wv;
    float x[6]; float s = 0.f;
#pragma unroll
    for (int k = 0; k < 6; ++k) { x[k] = q[(size_t)r*D + lane + 64*k]; s += x[k]*x[k]; }
#pragma unroll
    for (int o = 32; o > 0; o >>= 1) s += __shfl_xor(s, o);
    float inv = 1.0f / sqrtf(s);
#pragma unroll
    for (int k = 0; k < 6; ++k) {
      ushort_t rh = f2bf(x[k]);
      qrh[(size_t)r*D + lane + 64*k] = rh;
      qrl[(size_t)r*D + lane + 64*k] = f2bf(x[k] - bf2f(rh));
      qh [(size_t)r*D + lane + 64*k] = f2bf(x[k] * inv);
    }
  } else {
    int r = (bid - M/4 - B/4)*4 + wv;   // 0..1151
    const float* src; ushort_t* dh; ushort_t* dl;
    if (r < 384)      { src = W_ih + (size_t)r*D;       dh = wihh + (size_t)r*D;       dl = wihl + (size_t)r*D; }
    else if (r < 768) { src = W_hh + (size_t)(r-384)*D; dh = whhh + (size_t)(r-384)*D; dl = whhl + (size_t)(r-384)*D; }
    else              { src = W_g  + (size_t)(r-768)*D; dh = wgh  + (size_t)(r-768)*D; dl = wgl  + (size_t)(r-768)*D; }
#pragma unroll
    for (int k = 0; k < 6; ++k) {
      float v = src[lane + 64*k];
      ushort_t h = f2bf(v);
      dh[lane + 64*k] = h;
      dl[lane + 64*k] = f2bf(v - bf2f(h));
    }
  }
}

// ========== sim: 2-term split-bf16 32x32x16 MFMA, swizzled LDS ==========
// grid (B/128=8, NC=128), 256 threads = 4 waves (2x2), wave tile 64m x 64q
__global__ __launch_bounds__(256, 2) void k_sim(
    const ushort_t* __restrict__ qh,
    const ushort_t* __restrict__ mh, const ushort_t* __restrict__ ml,
    const float2* __restrict__ f2a, unsigned int* __restrict__ keybuf) {
  __shared__ __align__(16) ushort_t sQh[128*32];
  __shared__ __align__(16) ushort_t sMh[128*32];
  __shared__ __align__(16) ushort_t sMl[128*32];

  const int tid = threadIdx.x, lane = tid & 63, wave = tid >> 6;
  const int wr = wave >> 1, wc = wave & 1;
  const int l31 = lane & 31, half = lane >> 5;
  const int qb = blockIdx.x, nc = blockIdx.y;
  const int rowoff = lane >> 2, koff = swz_koff(lane);
  const int gsw = (l31 >> 1) & 3;          // read-side swizzle
  const size_t qrow0 = (size_t)qb * 128;

  unsigned int keys[2][3];
#pragma unroll
  for (int j = 0; j < 2; ++j) { keys[j][0] = 0; keys[j][1] = 0; keys[j][2] = 0; }

  for (int mt = 0; mt < 4; ++mt) {
    const size_t mrow0 = (size_t)nc * CHUNK + (size_t)mt * 128;
    f32x16 acc[2][2];
#pragma unroll
    for (int i = 0; i < 2; ++i)
#pragma unroll
      for (int j = 0; j < 2; ++j) acc[i][j] = (f32x16)0.0f;

    for (int kt = 0; kt < D; kt += 32) {
      __syncthreads();
#pragma unroll
      for (int n = 0; n < 6; ++n) {
        int f = wave*6 + n; int arr = f >> 3, slot = f & 7;
        const ushort_t* src = arr == 0 ? qh : (arr == 1 ? mh : ml);
        ushort_t* dst = arr == 0 ? sQh : (arr == 1 ? sMh : sMl);
        size_t rowb = arr == 0 ? qrow0 : mrow0;
        async16(src + (rowb + slot*16 + rowoff)*D + kt + koff,
                dst + slot*512 + lane*8);
      }
      __syncthreads();

      bf16x8 ah[2][2], al[2][2], bh[2][2];
#pragma unroll
      for (int i = 0; i < 2; ++i)
#pragma unroll
        for (int s = 0; s < 2; ++s) {
          int gra = ((s*2 + half) ^ gsw) * 8;
          int ro = (wr*64 + i*32 + l31)*32 + gra;
          ah[i][s] = *(const bf16x8*)&sMh[ro];
          al[i][s] = *(const bf16x8*)&sMl[ro];
          int co = (wc*64 + i*32 + l31)*32 + gra;
          bh[i][s] = *(const bf16x8*)&sQh[co];
        }
#pragma unroll
      for (int i = 0; i < 2; ++i)
#pragma unroll
        for (int j = 0; j < 2; ++j)
#pragma unroll
          for (int s = 0; s < 2; ++s) {
            acc[i][j] = __builtin_amdgcn_mfma_f32_32x32x16_bf16(ah[i][s], bh[j][s], acc[i][j], 0, 0, 0);
            acc[i][j] = __builtin_amdgcn_mfma_f32_32x32x16_bf16(al[i][s], bh[j][s], acc[i][j], 0, 0, 0);
          }
    }

    // epilogue: C layout col=lane&31, row=(r&3)+8*(r>>2)+4*half
#pragma unroll
    for (int i = 0; i < 2; ++i)
#pragma unroll
      for (int rg = 0; rg < 4; ++rg)
#pragma unroll
        for (int rr = 0; rr < 4; ++rr) {
          int rl = wr*64 + i*32 + half*4 + rr + 8*rg;
          float2 fa = f2a[mrow0 + rl];
          unsigned int idx = (unsigned int)(((nc & 1) << 9) | (mt*128 + rl));
          float v0 = fmaf(acc[i][0][rg*4+rr], fa.x, fa.y);
          insert3b(keys[0], (__float_as_uint(v0) & 0xFFFFFC00u) | idx);
          float v1 = fmaf(acc[i][1][rg*4+rr], fa.x, fa.y);
          insert3b(keys[1], (__float_as_uint(v1) & 0xFFFFFC00u) | idx);
        }
  }

#pragma unroll
  for (int j = 0; j < 2; ++j) {
    int q_local = wc*64 + j*32 + l31;
    int c = wr*2 + half;
    size_t off = ((size_t)(qb*128 + q_local) * NC + nc) * 12 + c*3;
    keybuf[off+0] = keys[j][0];
    keybuf[off+1] = keys[j][1];
    keybuf[off+2] = keys[j][2];
  }
}

// ============ merge candidates + exact fp32 rescore; wave per query =========
__global__ void k_merge(const unsigned int* __restrict__ keybuf,
                        const float* __restrict__ query, const float* __restrict__ memv,
                        const float2* __restrict__ f2b, int* __restrict__ topk) {
  int lane = threadIdx.x & 63, w = threadIdx.x >> 6;
  int q = blockIdx.x * 4 + w;

  // lane covers chunks 2*lane, 2*lane+1: 24 contiguous keys
  const unsigned int* kb = keybuf + (size_t)q * (NC*12) + (size_t)lane * 24;
  unsigned int k5[5] = {0,0,0,0,0};
#pragma unroll
  for (int c = 0; c < 6; ++c) {
    uint4 v = *(const uint4*)(kb + c*4);
    insert5b(k5, v.x); insert5b(k5, v.y); insert5b(k5, v.z); insert5b(k5, v.w);
  }

  int cand[16];
#pragma unroll
  for (int p = 0; p < 16; ++p) {
    unsigned int bk = k5[0]; int blv = lane;
#pragma unroll
    for (int off = 1; off < 64; off <<= 1) {
      unsigned int ok = (unsigned int)__shfl_xor((int)bk, off);
      int ol = __shfl_xor(blv, off);
      if (ok > bk || (ok == bk && ol < blv)) { bk = ok; blv = ol; }
    }
    cand[p] = (blv << 10) | (int)(bk & 1023u);
    if (lane == blv) { k5[0]=k5[1]; k5[1]=k5[2]; k5[2]=k5[3]; k5[3]=k5[4]; k5[4]=0; }
  }

  float qv[6]; float sq = 0.f;
#pragma unroll
  for (int k = 0; k < 6; ++k) { qv[k] = query[(size_t)q*D + lane + 64*k]; sq += qv[k]*qv[k]; }
#pragma unroll
  for (int o = 32; o > 0; o >>= 1) sq += __shfl_xor(sq, o);
  float qn = sqrtf(sq);

  float simv[16]; int simi[16];
#pragma unroll
  for (int p = 0; p < 16; ++p) {
    int mi = cand[p];
    float d = 0.f;
#pragma unroll
    for (int k = 0; k < 6; ++k) d += qv[k] * memv[(size_t)mi*D + lane + 64*k];
#pragma unroll
    for (int o = 32; o > 0; o >>= 1) d += __shfl_xor(d, o);
    float2 fb = f2b[mi];
    simv[p] = d / fmaxf(qn * fb.x, FEPS) + fb.y;
    simi[p] = mi;
  }
  if (lane == 0) {
    for (int s = 0; s < KK; ++s) {
      int best = -1; float bv = -1e30f; int bi = 0x7FFFFFFF;
      for (int p = 0; p < 16; ++p) {
        if (simi[p] < 0) continue;
        if (simv[p] > bv || (simv[p] == bv && simi[p] < bi)) { best = p; bv = simv[p]; bi = simi[p]; }
      }
      topk[q*KK + s] = simi[best];
      simi[best] = -1;
    }
  }
}

// ===== tail1: x_proj (gathered, 96 row-tiles) + gate (16 row-tiles) + h1 ====
// grid (112, 6); 64x64 tile, K=384 in 3 rounds of 4x32 subtiles; 3-term split
__global__ __launch_bounds__(256) void k_tail1(
    const ushort_t* __restrict__ qrh, const ushort_t* __restrict__ qrl,
    const ushort_t* __restrict__ mh, const ushort_t* __restrict__ ml,
    const int* __restrict__ topk,
    const ushort_t* __restrict__ wihh, const ushort_t* __restrict__ wihl,
    const ushort_t* __restrict__ wgh, const ushort_t* __restrict__ wgl,
    const float* __restrict__ b_ih, const float* __restrict__ b_hh,
    const float* __restrict__ b_g,
    float* __restrict__ xp, float* __restrict__ gate,
    ushort_t* __restrict__ hoh, ushort_t* __restrict__ hol) {
  __shared__ __align__(16) ushort_t sAh[64*128];
  __shared__ __align__(16) ushort_t sAl[64*128];
  __shared__ __align__(16) ushort_t sWh[64*128];
  __shared__ __align__(16) ushort_t sWl[64*128];

  const int tid = threadIdx.x, lane = tid & 63, wave = tid >> 6;
  const int wr = wave >> 1, wc = wave & 1;
  const int t = lane & 15, quad = lane >> 4;
  const bool xmode = blockIdx.x < 96;
  const int cbase = blockIdx.y * 64;
  const int rowoff = lane >> 2, koff = swz_koff(lane);
  const int pq = (quad ^ ((t >> 1) & 3)) * 8;    // swizzled read granule

  const ushort_t* gp[4];
  if (wave < 2) {
#pragma unroll
    for (int slot = 0; slot < 4; ++slot) {
      int rl = slot*16 + rowoff;
      const ushort_t* src;
      if (xmode) {
        int g = blockIdx.x*64 + rl;
        int b = g / 6, tt = g - b*6;
        if (tt == 0) src = (wave == 0 ? qrh : qrl) + (size_t)b * D;
        else         src = (wave == 0 ? mh  : ml ) + (size_t)topk[b*KK + tt - 1] * D;
      } else {
        int rq = (blockIdx.x - 96)*64 + rl;
        src = (wave == 0 ? qrh : qrl) + (size_t)rq * D;
      }
      gp[slot] = src + koff;
    }
  } else {
#pragma unroll
    for (int slot = 0; slot < 4; ++slot) {
      int rl = slot*16 + rowoff;
      const ushort_t* wsrc = xmode ? (wave == 2 ? wihh : wihl)
                                   : (wave == 2 ? wgh  : wgl);
      gp[slot] = wsrc + (size_t)(cbase + rl) * D + koff;
    }
  }
  ushort_t* ldst = (wave == 0) ? sAh : (wave == 1) ? sAl : (wave == 2) ? sWh : sWl;

  f32x4 acc[2][2];
#pragma unroll
  for (int i = 0; i < 2; ++i)
#pragma unroll
    for (int j = 0; j < 2; ++j) acc[i][j] = (f32x4)0.0f;

  for (int r3 = 0; r3 < 3; ++r3) {
    __syncthreads();
#pragma unroll
    for (int s = 0; s < 4; ++s)
#pragma unroll
      for (int slot = 0; slot < 4; ++slot)
        async16(gp[slot] + r3*128 + s*32, ldst + s*2048 + slot*512 + lane*8);
    __syncthreads();
#pragma unroll
    for (int s = 0; s < 4; ++s) {
      bf16x8 ah[2], al[2], bh[2], bl[2];
#pragma unroll
      for (int i = 0; i < 2; ++i) {
        int ro = s*2048 + (wr*32 + i*16 + t)*32 + pq;
        ah[i] = *(const bf16x8*)&sAh[ro];
        al[i] = *(const bf16x8*)&sAl[ro];
        int co = s*2048 + (wc*32 + i*16 + t)*32 + pq;
        bh[i] = *(const bf16x8*)&sWh[co];
        bl[i] = *(const bf16x8*)&sWl[co];
      }
#pragma unroll
      for (int i = 0; i < 2; ++i)
#pragma unroll
        for (int j = 0; j < 2; ++j) {
          acc[i][j] = __builtin_amdgcn_mfma_f32_16x16x32_bf16(ah[i], bh[j], acc[i][j], 0, 0, 0);
          acc[i][j] = __builtin_amdgcn_mfma_f32_16x16x32_bf16(ah[i], bl[j], acc[i][j], 0, 0, 0);
          acc[i][j] = __builtin_amdgcn_mfma_f32_16x16x32_bf16(al[i], bh[j], acc[i][j], 0, 0, 0);
        }
    }
  }

#pragma unroll
  for (int i = 0; i < 2; ++i)
#pragma unroll
    for (int j = 0; j < 2; ++j)
#pragma unroll
      for (int r = 0; r < 4; ++r) {
        int rloc = wr*32 + i*16 + quad*4 + r;
        int h = cbase + wc*32 + j*16 + t;
        float a = acc[i][j][r];
        if (xmode) {
          int g = blockIdx.x*64 + rloc;
          float v = a + b_ih[h];
          xp[(size_t)g*H + h] = v;
          int b = g / 6;
          if (g - b*6 == 0) {
            float hv = tanhf(v + b_hh[h]);
            ushort_t hi = f2bf(hv);
            hoh[(size_t)b*H + h] = hi;
            hol[(size_t)b*H + h] = f2bf(hv - bf2f(hi));
          }
        } else {
          int rq = (blockIdx.x - 96)*64 + rloc;
          gate[(size_t)rq*H + h] = 1.0f / (1.0f + expf(-(a + b_g[h])));
        }
      }
}

// ================= RNN step: h' = tanh(x_t + h @ W_hh^T + b_hh) =============
// grid (16, 6); LAST fuses the gated output blend
template<int LAST>
__global__ __launch_bounds__(256) void k_rnn(
    const ushort_t* __restrict__ hih, const ushort_t* __restrict__ hil,
    const ushort_t* __restrict__ whhh, const ushort_t* __restrict__ whhl,
    const float* __restrict__ b_hh, const float* __restrict__ xp,
    const float* __restrict__ gate, int step,
    ushort_t* __restrict__ hoh, ushort_t* __restrict__ hol,
    float* __restrict__ out) {
  __shared__ __align__(16) ushort_t sAh[64*128];
  __shared__ __align__(16) ushort_t sAl[64*128];
  __shared__ __align__(16) ushort_t sWh[64*128];
  __shared__ __align__(16) ushort_t sWl[64*128];

  const int tid = threadIdx.x, lane = tid & 63, wave = tid >> 6;
  const int wr = wave >> 1, wc = wave & 1;
  const int t = lane & 15, quad = lane >> 4;
  const int rbase = blockIdx.x * 64, cbase = blockIdx.y * 64;
  const int rowoff = lane >> 2, koff = swz_koff(lane);
  const int pq = (quad ^ ((t >> 1) & 3)) * 8;

  const ushort_t* gp[4];
#pragma unroll
  for (int slot = 0; slot < 4; ++slot) {
    int rl = slot*16 + rowoff;
    const ushort_t* src =
        (wave == 0) ? hih + (size_t)(rbase + rl)*D :
        (wave == 1) ? hil + (size_t)(rbase + rl)*D :
        (wave == 2) ? whhh + (size_t)(cbase + rl)*D :
                      whhl + (size_t)(cbase + rl)*D;
    gp[slot] = src + koff;
  }
  ushort_t* ldst = (wave == 0) ? sAh : (wave == 1) ? sAl : (wave == 2) ? sWh : sWl;

  f32x4 acc[2][2];
#pragma unroll
  for (int i = 0; i < 2; ++i)
#pragma unroll
    for (int j = 0; j < 2; ++j) acc[i][j] = (f32x4)0.0f;

  for (int r3 = 0; r3 < 3; ++r3) {
    __syncthreads();
#pragma unroll
    for (int s = 0; s < 4; ++s)
#pragma unroll
      for (int slot = 0; slot < 4; ++slot)
        async16(gp[slot] + r3*128 + s*32, ldst + s*2048 + slot*512 + lane*8);
    __syncthreads();
#pragma unroll
    for (int s = 0; s < 4; ++s) {
      bf16x8 ah[2], al[2], bh[2], bl[2];
#pragma unroll
      for (int i = 0; i < 2; ++i) {
        int ro = s*2048 + (wr*32 + i*16 + t)*32 + pq;
        ah[i] = *(const bf16x8*)&sAh[ro];
        al[i] = *(const bf16x8*)&sAl[ro];
        int co = s*2048 + (wc*32 + i*16 + t)*32 + pq;
        bh[i] = *(const bf16x8*)&sWh[co];
        bl[i] = *(const bf16x8*)&sWl[co];
      }
#pragma unroll
      for (int i = 0; i < 2; ++i)
#pragma unroll
        for (int j = 0; j < 2; ++j) {
          acc[i][j] = __builtin_amdgcn_mfma_f32_16x16x32_bf16(ah[i], bh[j], acc[i][j], 0, 0, 0);
          acc[i][j] = __builtin_amdgcn_mfma_f32_16x16x32_bf16(ah[i], bl[j], acc[i][j], 0, 0, 0);
          acc[i][j] = __builtin_amdgcn_mfma_f32_16x16x32_bf16(al[i], bh[j], acc[i][j], 0, 0, 0);
        }
    }
  }

#pragma unroll
  for (int i = 0; i < 2; ++i)
#pragma unroll
    for (int j = 0; j < 2; ++j)
#pragma unroll
      for (int r = 0; r < 4; ++r) {
        int row = rbase + wr*32 + i*16 + quad*4 + r;
        int h = cbase + wc*32 + j*16 + t;
        float v = acc[i][j][r] + b_hh[h] + xp[(size_t)row*(6*H) + step*H + h];
        float hv = tanhf(v);
        if (LAST) {
          float g = gate[(size_t)row*H + h];
          out[(size_t)row*H + h] = g*hv + (1.0f - g)*xp[(size_t)row*(6*H) + h];
        } else {
          ushort_t hi = f2bf(hv);
          hoh[(size_t)row*H + h] = hi;
          hol[(size_t)row*H + h] = f2bf(hv - bf2f(hi));
        }
      }
}

} // namespace

extern "C" void kernel_launch(void* const* d_in, const int* in_sizes, int n_in,
                              void* d_out, int out_size, void* d_ws, size_t ws_size,
                              hipStream_t stream) {
  const float* query = (const float*)d_in[0];
  const float* memv  = (const float*)d_in[1];
  const float* coords= (const float*)d_in[2];
  const float* sw    = (const float*)d_in[3];
  const float* W_ih  = (const float*)d_in[4];
  const float* b_ih  = (const float*)d_in[5];
  const float* W_hh  = (const float*)d_in[6];
  const float* b_hh  = (const float*)d_in[7];
  const float* W_g   = (const float*)d_in[8];
  const float* b_g   = (const float*)d_in[9];
  float* out = (float*)d_out;

  char* p = (char*)d_ws;
  auto alloc = [&](size_t bytes) {
    char* r = p; p += (bytes + 255) & ~(size_t)255; return r;
  };
  ushort_t* qh  = (ushort_t*)alloc((size_t)B * D * 2);
  ushort_t* qrh = (ushort_t*)alloc((size_t)B * D * 2);
  ushort_t* qrl = (ushort_t*)alloc((size_t)B * D * 2);
  ushort_t* mh  = (ushort_t*)alloc((size_t)M * D * 2);
  ushort_t* ml  = (ushort_t*)alloc((size_t)M * D * 2);
  float2* f2a   = (float2*)alloc((size_t)M * 8);
  float2* f2b   = (float2*)alloc((size_t)M * 8);
  ushort_t* wihh = (ushort_t*)alloc((size_t)H * D * 2);
  ushort_t* wihl = (ushort_t*)alloc((size_t)H * D * 2);
  ushort_t* whhh = (ushort_t*)alloc((size_t)H * D * 2);
  ushort_t* whhl = (ushort_t*)alloc((size_t)H * D * 2);
  ushort_t* wgh  = (ushort_t*)alloc((size_t)H * D * 2);
  ushort_t* wgl  = (ushort_t*)alloc((size_t)H * D * 2);
  unsigned int* keybuf = (unsigned int*)alloc((size_t)B * NC * 12 * 4);
  int*   topk   = (int*)alloc((size_t)B * KK * 4);
  float* xp     = (float*)alloc((size_t)B * 6 * H * 4);
  float* gate   = (float*)alloc((size_t)B * H * 4);
  ushort_t* hAh = (ushort_t*)alloc((size_t)B * H * 2);
  ushort_t* hAl = (ushort_t*)alloc((size_t)B * H * 2);
  ushort_t* hBh = (ushort_t*)alloc((size_t)B * H * 2);
  ushort_t* hBl = (ushort_t*)alloc((size_t)B * H * 2);

  k_prep<<<M/4 + B/4 + 288, 256, 0, stream>>>(
      query, memv, coords, sw, W_ih, W_hh, W_g,
      qh, qrh, qrl, mh, ml, f2a, f2b,
      wihh, wihl, whhh, whhl, wgh, wgl);
  k_sim<<<dim3(B/128, NC), 256, 0, stream>>>(qh, mh, ml, f2a, keybuf);
  k_merge<<<B/4, 256, 0, stream>>>(keybuf, query, memv, f2b, topk);
  k_tail1<<<dim3(112, 6), 256, 0, stream>>>(
      qrh, qrl, mh, ml, topk, wihh, wihl, wgh, wgl,
      b_ih, b_hh, b_g, xp, gate, hAh, hAl);
  k_rnn<0><<<dim3(16, 6), 256, 0, stream>>>(hAh, hAl, whhh, whhl, b_hh, xp, gate, 1, hBh, hBl, out);
  k_rnn<0><<<dim3(16, 6), 256, 0, stream>>>(hBh, hBl, whhh, whhl, b_hh, xp, gate, 2, hAh, hAl, out);
  k_rnn<0><<<dim3(16, 6), 256, 0, stream>>>(hAh, hAl, whhh, whhl, b_hh, xp, gate, 3, hBh, hBl, out);
  k_rnn<0><<<dim3(16, 6), 256, 0, stream>>>(hBh, hBl, whhh, whhl, b_hh, xp, gate, 4, hAh, hAl, out);
  k_rnn<1><<<dim3(16, 6), 256, 0, stream>>>(hAh, hAl, whhh, whhl, b_hh, xp, gate, 5, hBh, hBl, out);
}

// Round 6
// 419.069 us; speedup vs baseline: 1.2298x; 1.0709x over previous
//
#include <hip/hip_runtime.h>
#include <math.h>

namespace {

typedef float f32x4 __attribute__((ext_vector_type(4)));
typedef float f32x16 __attribute__((ext_vector_type(16)));
typedef short bf16x8 __attribute__((ext_vector_type(8)));
typedef unsigned short ushort_t;

constexpr int B  = 1024;
constexpr int M  = 65536;
constexpr int D  = 384;
constexpr int H  = 384;
constexpr int KK = 5;
constexpr int NC = 128;         // chunks over M
constexpr int CHUNK = M / NC;   // 512 mems per chunk
constexpr float FEPS = 1e-8f;

__device__ __forceinline__ ushort_t f2bf(float x) {
  unsigned int u = __float_as_uint(x);
  unsigned int r = (u + 0x7FFFu + ((u >> 16) & 1u)) >> 16;   // RNE
  return (ushort_t)r;
}
__device__ __forceinline__ float bf2f(ushort_t h) {
  return __uint_as_float(((unsigned int)h) << 16);
}

__device__ __forceinline__ void async16(const ushort_t* g, ushort_t* l) {
  __builtin_amdgcn_global_load_lds(
      (const __attribute__((address_space(1))) unsigned int*)g,
      (__attribute__((address_space(3))) unsigned int*)l, 16, 0, 0);
}

__device__ __forceinline__ void insert3b(unsigned int* k, unsigned int v) {
  unsigned int t0 = min(k[0], v); k[0] = max(k[0], v);
  unsigned int t1 = min(k[1], t0); k[1] = max(k[1], t0);
  k[2] = max(k[2], t1);
}
__device__ __forceinline__ void insert5b(unsigned int* k, unsigned int v) {
  unsigned int t0 = min(k[0], v); k[0] = max(k[0], v);
  unsigned int t1 = min(k[1], t0); k[1] = max(k[1], t0);
  unsigned int t2 = min(k[2], t1); k[2] = max(k[2], t1);
  unsigned int t3 = min(k[3], t2); k[3] = max(k[3], t2);
  k[4] = max(k[4], t3);
}

// swizzled per-lane global k-offset for staging: LDS granule (lane&3) of row
// (lane>>2) holds logical granule (lane&3) ^ ((row>>1)&3).  [bank-conflict fix]
__device__ __forceinline__ int swz_koff(int lane) {
  return (((lane & 3) ^ ((lane >> 3) & 3)) * 8);
}

// ================= mega prep: mem split+stats | q splits | weight splits ====
__global__ __launch_bounds__(256) void k_prep(
    const float* __restrict__ q, const float* __restrict__ mem,
    const float* __restrict__ coords, const float* __restrict__ sw,
    const float* __restrict__ W_ih, const float* __restrict__ W_hh,
    const float* __restrict__ W_g,
    ushort_t* __restrict__ qh, ushort_t* __restrict__ qrh, ushort_t* __restrict__ qrl,
    ushort_t* __restrict__ mh, ushort_t* __restrict__ ml,
    float2* __restrict__ f2a, float2* __restrict__ f2b,
    ushort_t* __restrict__ wihh, ushort_t* __restrict__ wihl,
    ushort_t* __restrict__ whhh, ushort_t* __restrict__ whhl,
    ushort_t* __restrict__ wgh, ushort_t* __restrict__ wgl) {
  int wv = threadIdx.x >> 6, lane = threadIdx.x & 63;
  int bid = blockIdx.x;
  if (bid < M/4) {
    int r = bid*4 + wv;
    float cx = 0.f, cy = 0.f;
    for (int i = lane; i < H; i += 64) { cx += sw[2*i]; cy += sw[2*i+1]; }
#pragma unroll
    for (int o = 32; o > 0; o >>= 1) { cx += __shfl_xor(cx, o); cy += __shfl_xor(cy, o); }
    cx *= (1.0f/384.0f); cy *= (1.0f/384.0f);
    float x[6]; float s = 0.f;
#pragma unroll
    for (int k = 0; k < 6; ++k) { x[k] = mem[(size_t)r*D + lane + 64*k]; s += x[k]*x[k]; }
#pragma unroll
    for (int o = 32; o > 0; o >>= 1) s += __shfl_xor(s, o);
#pragma unroll
    for (int k = 0; k < 6; ++k) {
      ushort_t h = f2bf(x[k]);
      mh[(size_t)r*D + lane + 64*k] = h;
      ml[(size_t)r*D + lane + 64*k] = f2bf(x[k] - bf2f(h));
    }
    if (lane == 0) {
      float mn = sqrtf(s);
      float dx = coords[2*r] - cx, dy = coords[2*r+1] - cy;
      float act = 1.0f / (1.0f + sqrtf(dx*dx + dy*dy));
      f2a[r] = make_float2(1.0f / mn, act + 2.0f);
      f2b[r] = make_float2(mn, act);
    }
  } else if (bid < M/4 + B/4) {
    int r = (bid - M/4)*4 + wv;
    float x[6]; float s = 0.f;
#pragma unroll
    for (int k = 0; k < 6; ++k) { x[k] = q[(size_t)r*D + lane + 64*k]; s += x[k]*x[k]; }
#pragma unroll
    for (int o = 32; o > 0; o >>= 1) s += __shfl_xor(s, o);
    float inv = 1.0f / sqrtf(s);
#pragma unroll
    for (int k = 0; k < 6; ++k) {
      ushort_t rh = f2bf(x[k]);
      qrh[(size_t)r*D + lane + 64*k] = rh;
      qrl[(size_t)r*D + lane + 64*k] = f2bf(x[k] - bf2f(rh));
      qh [(size_t)r*D + lane + 64*k] = f2bf(x[k] * inv);
    }
  } else {
    int r = (bid - M/4 - B/4)*4 + wv;   // 0..1151
    const float* src; ushort_t* dh; ushort_t* dl;
    if (r < 384)      { src = W_ih + (size_t)r*D;       dh = wihh + (size_t)r*D;       dl = wihl + (size_t)r*D; }
    else if (r < 768) { src = W_hh + (size_t)(r-384)*D; dh = whhh + (size_t)(r-384)*D; dl = whhl + (size_t)(r-384)*D; }
    else              { src = W_g  + (size_t)(r-768)*D; dh = wgh  + (size_t)(r-768)*D; dl = wgl  + (size_t)(r-768)*D; }
#pragma unroll
    for (int k = 0; k < 6; ++k) {
      float v = src[lane + 64*k];
      ushort_t h = f2bf(v);
      dh[lane + 64*k] = h;
      dl[lane + 64*k] = f2bf(v - bf2f(h));
    }
  }
}

// ========== sim: 2-term split-bf16 32x32x16 MFMA, swizzled LDS ==========
// 1D grid 1024; XCD-aware decode: the 8 q-tiles sharing chunk nc are
// consecutive on XCD nc%8 -> chunk read from HBM once, L2-hit 7x.
__global__ __launch_bounds__(256, 2) void k_sim(
    const ushort_t* __restrict__ qh,
    const ushort_t* __restrict__ mh, const ushort_t* __restrict__ ml,
    const float2* __restrict__ f2a, unsigned int* __restrict__ keybuf) {
  __shared__ __align__(16) ushort_t sQh[128*32];
  __shared__ __align__(16) ushort_t sMh[128*32];
  __shared__ __align__(16) ushort_t sMl[128*32];
  __shared__ __align__(16) float2 sF[CHUNK];   // per-chunk (1/mn, act+2)

  const int tid = threadIdx.x, lane = tid & 63, wave = tid >> 6;
  const int wr = wave >> 1, wc = wave & 1;
  const int l31 = lane & 31, half = lane >> 5;
  const int flat = blockIdx.x;
  const int k8 = flat & 7, qb = (flat >> 3) & 7, mgrp = flat >> 6;
  const int nc = (mgrp << 3) | k8;
  const int rowoff = lane >> 2, koff = swz_koff(lane);
  const int gsw = (l31 >> 1) & 3;          // read-side swizzle
  const size_t qrow0 = (size_t)qb * 128;

  // stage chunk stats once (coalesced): 256 x float4 = 512 float2
  ((float4*)sF)[tid] = ((const float4*)(f2a + (size_t)nc * CHUNK))[tid];

  unsigned int keys[2][3];
#pragma unroll
  for (int j = 0; j < 2; ++j) { keys[j][0] = 0; keys[j][1] = 0; keys[j][2] = 0; }

  for (int mt = 0; mt < 4; ++mt) {
    const size_t mrow0 = (size_t)nc * CHUNK + (size_t)mt * 128;
    f32x16 acc[2][2];
#pragma unroll
    for (int i = 0; i < 2; ++i)
#pragma unroll
      for (int j = 0; j < 2; ++j) acc[i][j] = (f32x16)0.0f;

    for (int kt = 0; kt < D; kt += 32) {
      __syncthreads();
#pragma unroll
      for (int n = 0; n < 6; ++n) {
        int f = wave*6 + n; int arr = f >> 3, slot = f & 7;
        const ushort_t* src = arr == 0 ? qh : (arr == 1 ? mh : ml);
        ushort_t* dst = arr == 0 ? sQh : (arr == 1 ? sMh : sMl);
        size_t rowb = arr == 0 ? qrow0 : mrow0;
        async16(src + (rowb + slot*16 + rowoff)*D + kt + koff,
                dst + slot*512 + lane*8);
      }
      __syncthreads();

      bf16x8 ah[2][2], al[2][2], bh[2][2];
#pragma unroll
      for (int i = 0; i < 2; ++i)
#pragma unroll
        for (int s = 0; s < 2; ++s) {
          int gra = ((s*2 + half) ^ gsw) * 8;
          int ro = (wr*64 + i*32 + l31)*32 + gra;
          ah[i][s] = *(const bf16x8*)&sMh[ro];
          al[i][s] = *(const bf16x8*)&sMl[ro];
          int co = (wc*64 + i*32 + l31)*32 + gra;
          bh[i][s] = *(const bf16x8*)&sQh[co];
        }
#pragma unroll
      for (int i = 0; i < 2; ++i)
#pragma unroll
        for (int j = 0; j < 2; ++j)
#pragma unroll
          for (int s = 0; s < 2; ++s) {
            acc[i][j] = __builtin_amdgcn_mfma_f32_32x32x16_bf16(ah[i][s], bh[j][s], acc[i][j], 0, 0, 0);
            acc[i][j] = __builtin_amdgcn_mfma_f32_32x32x16_bf16(al[i][s], bh[j][s], acc[i][j], 0, 0, 0);
          }
    }

    // epilogue: C layout col=lane&31, row=(r&3)+8*(r>>2)+4*half; stats from LDS
#pragma unroll
    for (int i = 0; i < 2; ++i)
#pragma unroll
      for (int rg = 0; rg < 4; ++rg)
#pragma unroll
        for (int rr = 0; rr < 4; ++rr) {
          int rl = wr*64 + i*32 + half*4 + rr + 8*rg;
          float2 fa = sF[mt*128 + rl];
          unsigned int idx = (unsigned int)(((nc & 1) << 9) | (mt*128 + rl));
          float v0 = fmaf(acc[i][0][rg*4+rr], fa.x, fa.y);
          insert3b(keys[0], (__float_as_uint(v0) & 0xFFFFFC00u) | idx);
          float v1 = fmaf(acc[i][1][rg*4+rr], fa.x, fa.y);
          insert3b(keys[1], (__float_as_uint(v1) & 0xFFFFFC00u) | idx);
        }
  }

#pragma unroll
  for (int j = 0; j < 2; ++j) {
    int q_local = wc*64 + j*32 + l31;
    int c = wr*2 + half;
    size_t off = ((size_t)(qb*128 + q_local) * NC + nc) * 12 + c*3;
    keybuf[off+0] = keys[j][0];
    keybuf[off+1] = keys[j][1];
    keybuf[off+2] = keys[j][2];
  }
}

// ============ merge candidates + exact fp32 rescore; wave per query =========
__global__ void k_merge(const unsigned int* __restrict__ keybuf,
                        const float* __restrict__ query, const float* __restrict__ memv,
                        const float2* __restrict__ f2b, int* __restrict__ topk) {
  int lane = threadIdx.x & 63, w = threadIdx.x >> 6;
  int q = blockIdx.x * 4 + w;

  // lane covers chunks 2*lane, 2*lane+1: 24 contiguous keys
  const unsigned int* kb = keybuf + (size_t)q * (NC*12) + (size_t)lane * 24;
  unsigned int k5[5] = {0,0,0,0,0};
#pragma unroll
  for (int c = 0; c < 6; ++c) {
    uint4 v = *(const uint4*)(kb + c*4);
    insert5b(k5, v.x); insert5b(k5, v.y); insert5b(k5, v.z); insert5b(k5, v.w);
  }

  int cand[16];
#pragma unroll
  for (int p = 0; p < 16; ++p) {
    unsigned int bk = k5[0]; int blv = lane;
#pragma unroll
    for (int off = 1; off < 64; off <<= 1) {
      unsigned int ok = (unsigned int)__shfl_xor((int)bk, off);
      int ol = __shfl_xor(blv, off);
      if (ok > bk || (ok == bk && ol < blv)) { bk = ok; blv = ol; }
    }
    cand[p] = (blv << 10) | (int)(bk & 1023u);
    if (lane == blv) { k5[0]=k5[1]; k5[1]=k5[2]; k5[2]=k5[3]; k5[3]=k5[4]; k5[4]=0; }
  }

  float qv[6]; float sq = 0.f;
#pragma unroll
  for (int k = 0; k < 6; ++k) { qv[k] = query[(size_t)q*D + lane + 64*k]; sq += qv[k]*qv[k]; }
#pragma unroll
  for (int o = 32; o > 0; o >>= 1) sq += __shfl_xor(sq, o);
  float qn = sqrtf(sq);

  float simv[16]; int simi[16];
#pragma unroll
  for (int p = 0; p < 16; ++p) {
    int mi = cand[p];
    float d = 0.f;
#pragma unroll
    for (int k = 0; k < 6; ++k) d += qv[k] * memv[(size_t)mi*D + lane + 64*k];
#pragma unroll
    for (int o = 32; o > 0; o >>= 1) d += __shfl_xor(d, o);
    float2 fb = f2b[mi];
    simv[p] = d / fmaxf(qn * fb.x, FEPS) + fb.y;
    simi[p] = mi;
  }
  if (lane == 0) {
    for (int s = 0; s < KK; ++s) {
      int best = -1; float bv = -1e30f; int bi = 0x7FFFFFFF;
      for (int p = 0; p < 16; ++p) {
        if (simi[p] < 0) continue;
        if (simv[p] > bv || (simv[p] == bv && simi[p] < bi)) { best = p; bv = simv[p]; bi = simi[p]; }
      }
      topk[q*KK + s] = simi[best];
      simi[best] = -1;
    }
  }
}

// ===== tail1: x_proj (gathered, 96 row-tiles) + gate (16 row-tiles) + h1 ====
// grid (112, 6); 64x64 tile, K=384 in 3 rounds of 4x32 subtiles; 3-term split
__global__ __launch_bounds__(256) void k_tail1(
    const ushort_t* __restrict__ qrh, const ushort_t* __restrict__ qrl,
    const ushort_t* __restrict__ mh, const ushort_t* __restrict__ ml,
    const int* __restrict__ topk,
    const ushort_t* __restrict__ wihh, const ushort_t* __restrict__ wihl,
    const ushort_t* __restrict__ wgh, const ushort_t* __restrict__ wgl,
    const float* __restrict__ b_ih, const float* __restrict__ b_hh,
    const float* __restrict__ b_g,
    float* __restrict__ xp, float* __restrict__ gate,
    ushort_t* __restrict__ hoh, ushort_t* __restrict__ hol) {
  __shared__ __align__(16) ushort_t sAh[64*128];
  __shared__ __align__(16) ushort_t sAl[64*128];
  __shared__ __align__(16) ushort_t sWh[64*128];
  __shared__ __align__(16) ushort_t sWl[64*128];

  const int tid = threadIdx.x, lane = tid & 63, wave = tid >> 6;
  const int wr = wave >> 1, wc = wave & 1;
  const int t = lane & 15, quad = lane >> 4;
  const bool xmode = blockIdx.x < 96;
  const int cbase = blockIdx.y * 64;
  const int rowoff = lane >> 2, koff = swz_koff(lane);
  const int pq = (quad ^ ((t >> 1) & 3)) * 8;    // swizzled read granule

  const ushort_t* gp[4];
  if (wave < 2) {
#pragma unroll
    for (int slot = 0; slot < 4; ++slot) {
      int rl = slot*16 + rowoff;
      const ushort_t* src;
      if (xmode) {
        int g = blockIdx.x*64 + rl;
        int b = g / 6, tt = g - b*6;
        if (tt == 0) src = (wave == 0 ? qrh : qrl) + (size_t)b * D;
        else         src = (wave == 0 ? mh  : ml ) + (size_t)topk[b*KK + tt - 1] * D;
      } else {
        int rq = (blockIdx.x - 96)*64 + rl;
        src = (wave == 0 ? qrh : qrl) + (size_t)rq * D;
      }
      gp[slot] = src + koff;
    }
  } else {
#pragma unroll
    for (int slot = 0; slot < 4; ++slot) {
      int rl = slot*16 + rowoff;
      const ushort_t* wsrc = xmode ? (wave == 2 ? wihh : wihl)
                                   : (wave == 2 ? wgh  : wgl);
      gp[slot] = wsrc + (size_t)(cbase + rl) * D + koff;
    }
  }
  ushort_t* ldst = (wave == 0) ? sAh : (wave == 1) ? sAl : (wave == 2) ? sWh : sWl;

  f32x4 acc[2][2];
#pragma unroll
  for (int i = 0; i < 2; ++i)
#pragma unroll
    for (int j = 0; j < 2; ++j) acc[i][j] = (f32x4)0.0f;

  for (int r3 = 0; r3 < 3; ++r3) {
    __syncthreads();
#pragma unroll
    for (int s = 0; s < 4; ++s)
#pragma unroll
      for (int slot = 0; slot < 4; ++slot)
        async16(gp[slot] + r3*128 + s*32, ldst + s*2048 + slot*512 + lane*8);
    __syncthreads();
#pragma unroll
    for (int s = 0; s < 4; ++s) {
      bf16x8 ah[2], al[2], bh[2], bl[2];
#pragma unroll
      for (int i = 0; i < 2; ++i) {
        int ro = s*2048 + (wr*32 + i*16 + t)*32 + pq;
        ah[i] = *(const bf16x8*)&sAh[ro];
        al[i] = *(const bf16x8*)&sAl[ro];
        int co = s*2048 + (wc*32 + i*16 + t)*32 + pq;
        bh[i] = *(const bf16x8*)&sWh[co];
        bl[i] = *(const bf16x8*)&sWl[co];
      }
#pragma unroll
      for (int i = 0; i < 2; ++i)
#pragma unroll
        for (int j = 0; j < 2; ++j) {
          acc[i][j] = __builtin_amdgcn_mfma_f32_16x16x32_bf16(ah[i], bh[j], acc[i][j], 0, 0, 0);
          acc[i][j] = __builtin_amdgcn_mfma_f32_16x16x32_bf16(ah[i], bl[j], acc[i][j], 0, 0, 0);
          acc[i][j] = __builtin_amdgcn_mfma_f32_16x16x32_bf16(al[i], bh[j], acc[i][j], 0, 0, 0);
        }
    }
  }

#pragma unroll
  for (int i = 0; i < 2; ++i)
#pragma unroll
    for (int j = 0; j < 2; ++j)
#pragma unroll
      for (int r = 0; r < 4; ++r) {
        int rloc = wr*32 + i*16 + quad*4 + r;
        int h = cbase + wc*32 + j*16 + t;
        float a = acc[i][j][r];
        if (xmode) {
          int g = blockIdx.x*64 + rloc;
          float v = a + b_ih[h];
          xp[(size_t)g*H + h] = v;
          int b = g / 6;
          if (g - b*6 == 0) {
            float hv = tanhf(v + b_hh[h]);
            ushort_t hi = f2bf(hv);
            hoh[(size_t)b*H + h] = hi;
            hol[(size_t)b*H + h] = f2bf(hv - bf2f(hi));
          }
        } else {
          int rq = (blockIdx.x - 96)*64 + rloc;
          gate[(size_t)rq*H + h] = 1.0f / (1.0f + expf(-(a + b_g[h])));
        }
      }
}

// ================= RNN step: h' = tanh(x_t + h @ W_hh^T + b_hh) =============
// grid (16, 6); LAST fuses the gated output blend
template<int LAST>
__global__ __launch_bounds__(256) void k_rnn(
    const ushort_t* __restrict__ hih, const ushort_t* __restrict__ hil,
    const ushort_t* __restrict__ whhh, const ushort_t* __restrict__ whhl,
    const float* __restrict__ b_hh, const float* __restrict__ xp,
    const float* __restrict__ gate, int step,
    ushort_t* __restrict__ hoh, ushort_t* __restrict__ hol,
    float* __restrict__ out) {
  __shared__ __align__(16) ushort_t sAh[64*128];
  __shared__ __align__(16) ushort_t sAl[64*128];
  __shared__ __align__(16) ushort_t sWh[64*128];
  __shared__ __align__(16) ushort_t sWl[64*128];

  const int tid = threadIdx.x, lane = tid & 63, wave = tid >> 6;
  const int wr = wave >> 1, wc = wave & 1;
  const int t = lane & 15, quad = lane >> 4;
  const int rbase = blockIdx.x * 64, cbase = blockIdx.y * 64;
  const int rowoff = lane >> 2, koff = swz_koff(lane);
  const int pq = (quad ^ ((t >> 1) & 3)) * 8;

  const ushort_t* gp[4];
#pragma unroll
  for (int slot = 0; slot < 4; ++slot) {
    int rl = slot*16 + rowoff;
    const ushort_t* src =
        (wave == 0) ? hih + (size_t)(rbase + rl)*D :
        (wave == 1) ? hil + (size_t)(rbase + rl)*D :
        (wave == 2) ? whhh + (size_t)(cbase + rl)*D :
                      whhl + (size_t)(cbase + rl)*D;
    gp[slot] = src + koff;
  }
  ushort_t* ldst = (wave == 0) ? sAh : (wave == 1) ? sAl : (wave == 2) ? sWh : sWl;

  f32x4 acc[2][2];
#pragma unroll
  for (int i = 0; i < 2; ++i)
#pragma unroll
    for (int j = 0; j < 2; ++j) acc[i][j] = (f32x4)0.0f;

  for (int r3 = 0; r3 < 3; ++r3) {
    __syncthreads();
#pragma unroll
    for (int s = 0; s < 4; ++s)
#pragma unroll
      for (int slot = 0; slot < 4; ++slot)
        async16(gp[slot] + r3*128 + s*32, ldst + s*2048 + slot*512 + lane*8);
    __syncthreads();
#pragma unroll
    for (int s = 0; s < 4; ++s) {
      bf16x8 ah[2], al[2], bh[2], bl[2];
#pragma unroll
      for (int i = 0; i < 2; ++i) {
        int ro = s*2048 + (wr*32 + i*16 + t)*32 + pq;
        ah[i] = *(const bf16x8*)&sAh[ro];
        al[i] = *(const bf16x8*)&sAl[ro];
        int co = s*2048 + (wc*32 + i*16 + t)*32 + pq;
        bh[i] = *(const bf16x8*)&sWh[co];
        bl[i] = *(const bf16x8*)&sWl[co];
      }
#pragma unroll
      for (int i = 0; i < 2; ++i)
#pragma unroll
        for (int j = 0; j < 2; ++j) {
          acc[i][j] = __builtin_amdgcn_mfma_f32_16x16x32_bf16(ah[i], bh[j], acc[i][j], 0, 0, 0);
          acc[i][j] = __builtin_amdgcn_mfma_f32_16x16x32_bf16(ah[i], bl[j], acc[i][j], 0, 0, 0);
          acc[i][j] = __builtin_amdgcn_mfma_f32_16x16x32_bf16(al[i], bh[j], acc[i][j], 0, 0, 0);
        }
    }
  }

#pragma unroll
  for (int i = 0; i < 2; ++i)
#pragma unroll
    for (int j = 0; j < 2; ++j)
#pragma unroll
      for (int r = 0; r < 4; ++r) {
        int row = rbase + wr*32 + i*16 + quad*4 + r;
        int h = cbase + wc*32 + j*16 + t;
        float v = acc[i][j][r] + b_hh[h] + xp[(size_t)row*(6*H) + step*H + h];
        float hv = tanhf(v);
        if (LAST) {
          float g = gate[(size_t)row*H + h];
          out[(size_t)row*H + h] = g*hv + (1.0f - g)*xp[(size_t)row*(6*H) + h];
        } else {
          ushort_t hi = f2bf(hv);
          hoh[(size_t)row*H + h] = hi;
          hol[(size_t)row*H + h] = f2bf(hv - bf2f(hi));
        }
      }
}

} // namespace

extern "C" void kernel_launch(void* const* d_in, const int* in_sizes, int n_in,
                              void* d_out, int out_size, void* d_ws, size_t ws_size,
                              hipStream_t stream) {
  const float* query = (const float*)d_in[0];
  const float* memv  = (const float*)d_in[1];
  const float* coords= (const float*)d_in[2];
  const float* sw    = (const float*)d_in[3];
  const float* W_ih  = (const float*)d_in[4];
  const float* b_ih  = (const float*)d_in[5];
  const float* W_hh  = (const float*)d_in[6];
  const float* b_hh  = (const float*)d_in[7];
  const float* W_g   = (const float*)d_in[8];
  const float* b_g   = (const float*)d_in[9];
  float* out = (float*)d_out;

  char* p = (char*)d_ws;
  auto alloc = [&](size_t bytes) {
    char* r = p; p += (bytes + 255) & ~(size_t)255; return r;
  };
  ushort_t* qh  = (ushort_t*)alloc((size_t)B * D * 2);
  ushort_t* qrh = (ushort_t*)alloc((size_t)B * D * 2);
  ushort_t* qrl = (ushort_t*)alloc((size_t)B * D * 2);
  ushort_t* mh  = (ushort_t*)alloc((size_t)M * D * 2);
  ushort_t* ml  = (ushort_t*)alloc((size_t)M * D * 2);
  float2* f2a   = (float2*)alloc((size_t)M * 8);
  float2* f2b   = (float2*)alloc((size_t)M * 8);
  ushort_t* wihh = (ushort_t*)alloc((size_t)H * D * 2);
  ushort_t* wihl = (ushort_t*)alloc((size_t)H * D * 2);
  ushort_t* whhh = (ushort_t*)alloc((size_t)H * D * 2);
  ushort_t* whhl = (ushort_t*)alloc((size_t)H * D * 2);
  ushort_t* wgh  = (ushort_t*)alloc((size_t)H * D * 2);
  ushort_t* wgl  = (ushort_t*)alloc((size_t)H * D * 2);
  unsigned int* keybuf = (unsigned int*)alloc((size_t)B * NC * 12 * 4);
  int*   topk   = (int*)alloc((size_t)B * KK * 4);
  float* xp     = (float*)alloc((size_t)B * 6 * H * 4);
  float* gate   = (float*)alloc((size_t)B * H * 4);
  ushort_t* hAh = (ushort_t*)alloc((size_t)B * H * 2);
  ushort_t* hAl = (ushort_t*)alloc((size_t)B * H * 2);
  ushort_t* hBh = (ushort_t*)alloc((size_t)B * H * 2);
  ushort_t* hBl = (ushort_t*)alloc((size_t)B * H * 2);

  k_prep<<<M/4 + B/4 + 288, 256, 0, stream>>>(
      query, memv, coords, sw, W_ih, W_hh, W_g,
      qh, qrh, qrl, mh, ml, f2a, f2b,
      wihh, wihl, whhh, whhl, wgh, wgl);
  k_sim<<<1024, 256, 0, stream>>>(qh, mh, ml, f2a, keybuf);
  k_merge<<<B/4, 256, 0, stream>>>(keybuf, query, memv, f2b, topk);
  k_tail1<<<dim3(112, 6), 256, 0, stream>>>(
      qrh, qrl, mh, ml, topk, wihh, wihl, wgh, wgl,
      b_ih, b_hh, b_g, xp, gate, hAh, hAl);
  k_rnn<0><<<dim3(16, 6), 256, 0, stream>>>(hAh, hAl, whhh, whhl, b_hh, xp, gate, 1, hBh, hBl, out);
  k_rnn<0><<<dim3(16, 6), 256, 0, stream>>>(hBh, hBl, whhh, whhl, b_hh, xp, gate, 2, hAh, hAl, out);
  k_rnn<0><<<dim3(16, 6), 256, 0, stream>>>(hAh, hAl, whhh, whhl, b_hh, xp, gate, 3, hBh, hBl, out);
  k_rnn<0><<<dim3(16, 6), 256, 0, stream>>>(hBh, hBl, whhh, whhl, b_hh, xp, gate, 4, hAh, hAl, out);
  k_rnn<1><<<dim3(16, 6), 256, 0, stream>>>(hAh, hAl, whhh, whhl, b_hh, xp, gate, 5, hBh, hBl, out);
}

// Round 7
// 409.496 us; speedup vs baseline: 1.2585x; 1.0234x over previous
//
#include <hip/hip_runtime.h>
#include <math.h>

namespace {

typedef float f32x4 __attribute__((ext_vector_type(4)));
typedef float f32x16 __attribute__((ext_vector_type(16)));
typedef short bf16x8 __attribute__((ext_vector_type(8)));
typedef unsigned short ushort_t;

constexpr int B  = 1024;
constexpr int M  = 65536;
constexpr int D  = 384;
constexpr int H  = 384;
constexpr int KK = 5;
constexpr int NC = 128;         // chunks over M
constexpr int CHUNK = M / NC;   // 512 mems per chunk
constexpr float FEPS = 1e-8f;

__device__ __forceinline__ ushort_t f2bf(float x) {
  unsigned int u = __float_as_uint(x);
  unsigned int r = (u + 0x7FFFu + ((u >> 16) & 1u)) >> 16;   // RNE
  return (ushort_t)r;
}
__device__ __forceinline__ float bf2f(ushort_t h) {
  return __uint_as_float(((unsigned int)h) << 16);
}

__device__ __forceinline__ void async16(const ushort_t* g, ushort_t* l) {
  __builtin_amdgcn_global_load_lds(
      (const __attribute__((address_space(1))) unsigned int*)g,
      (__attribute__((address_space(3))) unsigned int*)l, 16, 0, 0);
}

__device__ __forceinline__ void insert3b(unsigned int* k, unsigned int v) {
  unsigned int t0 = min(k[0], v); k[0] = max(k[0], v);
  unsigned int t1 = min(k[1], t0); k[1] = max(k[1], t0);
  k[2] = max(k[2], t1);
}
__device__ __forceinline__ void insert5b(unsigned int* k, unsigned int v) {
  unsigned int t0 = min(k[0], v); k[0] = max(k[0], v);
  unsigned int t1 = min(k[1], t0); k[1] = max(k[1], t0);
  unsigned int t2 = min(k[2], t1); k[2] = max(k[2], t1);
  unsigned int t3 = min(k[3], t2); k[3] = max(k[3], t2);
  k[4] = max(k[4], t3);
}

// swizzled per-lane global k-offset for staging: LDS granule (lane&3) of row
// (lane>>2) holds logical granule (lane&3) ^ ((row>>1)&3).  [bank-conflict fix]
__device__ __forceinline__ int swz_koff(int lane) {
  return (((lane & 3) ^ ((lane >> 3) & 3)) * 8);
}

// ================= mega prep: mem split+stats | q splits | weight splits ====
// lane handles 2 consecutive elements: float2 reads, ushort2 writes (full-width stores)
__global__ __launch_bounds__(256) void k_prep(
    const float* __restrict__ q, const float* __restrict__ mem,
    const float* __restrict__ coords, const float* __restrict__ sw,
    const float* __restrict__ W_ih, const float* __restrict__ W_hh,
    const float* __restrict__ W_g,
    ushort_t* __restrict__ qh, ushort_t* __restrict__ qrh, ushort_t* __restrict__ qrl,
    ushort_t* __restrict__ mh, ushort_t* __restrict__ ml,
    float2* __restrict__ f2a, float2* __restrict__ f2b,
    ushort_t* __restrict__ wihh, ushort_t* __restrict__ wihl,
    ushort_t* __restrict__ whhh, ushort_t* __restrict__ whhl,
    ushort_t* __restrict__ wgh, ushort_t* __restrict__ wgl) {
  int wv = threadIdx.x >> 6, lane = threadIdx.x & 63;
  int bid = blockIdx.x;
  if (bid < M/4) {
    int r = bid*4 + wv;
    float cx = 0.f, cy = 0.f;
    for (int i = lane; i < H; i += 64) { cx += sw[2*i]; cy += sw[2*i+1]; }
#pragma unroll
    for (int o = 32; o > 0; o >>= 1) { cx += __shfl_xor(cx, o); cy += __shfl_xor(cy, o); }
    cx *= (1.0f/384.0f); cy *= (1.0f/384.0f);
    float2 x[3]; float s = 0.f;
#pragma unroll
    for (int k = 0; k < 3; ++k) {
      x[k] = ((const float2*)(mem + (size_t)r*D))[lane + 64*k];
      s += x[k].x*x[k].x + x[k].y*x[k].y;
    }
#pragma unroll
    for (int o = 32; o > 0; o >>= 1) s += __shfl_xor(s, o);
#pragma unroll
    for (int k = 0; k < 3; ++k) {
      ushort_t h0 = f2bf(x[k].x), h1 = f2bf(x[k].y);
      ushort2 hh; hh.x = h0; hh.y = h1;
      ushort2 ll; ll.x = f2bf(x[k].x - bf2f(h0)); ll.y = f2bf(x[k].y - bf2f(h1));
      ((ushort2*)(mh + (size_t)r*D))[lane + 64*k] = hh;
      ((ushort2*)(ml + (size_t)r*D))[lane + 64*k] = ll;
    }
    if (lane == 0) {
      float mn = sqrtf(s);
      float dx = coords[2*r] - cx, dy = coords[2*r+1] - cy;
      float act = 1.0f / (1.0f + sqrtf(dx*dx + dy*dy));
      f2a[r] = make_float2(1.0f / mn, act + 2.0f);
      f2b[r] = make_float2(mn, act);
    }
  } else if (bid < M/4 + B/4) {
    int r = (bid - M/4)*4 + wv;
    float2 x[3]; float s = 0.f;
#pragma unroll
    for (int k = 0; k < 3; ++k) {
      x[k] = ((const float2*)(q + (size_t)r*D))[lane + 64*k];
      s += x[k].x*x[k].x + x[k].y*x[k].y;
    }
#pragma unroll
    for (int o = 32; o > 0; o >>= 1) s += __shfl_xor(s, o);
    float inv = 1.0f / sqrtf(s);
#pragma unroll
    for (int k = 0; k < 3; ++k) {
      ushort_t h0 = f2bf(x[k].x), h1 = f2bf(x[k].y);
      ushort2 hh; hh.x = h0; hh.y = h1;
      ushort2 ll; ll.x = f2bf(x[k].x - bf2f(h0)); ll.y = f2bf(x[k].y - bf2f(h1));
      ((ushort2*)(qrh + (size_t)r*D))[lane + 64*k] = hh;
      ((ushort2*)(qrl + (size_t)r*D))[lane + 64*k] = ll;
      ushort2 nn; nn.x = f2bf(x[k].x * inv); nn.y = f2bf(x[k].y * inv);
      ((ushort2*)(qh + (size_t)r*D))[lane + 64*k] = nn;
    }
  } else {
    int r = (bid - M/4 - B/4)*4 + wv;   // 0..1151
    const float* src; ushort_t* dh; ushort_t* dl;
    if (r < 384)      { src = W_ih + (size_t)r*D;       dh = wihh + (size_t)r*D;       dl = wihl + (size_t)r*D; }
    else if (r < 768) { src = W_hh + (size_t)(r-384)*D; dh = whhh + (size_t)(r-384)*D; dl = whhl + (size_t)(r-384)*D; }
    else              { src = W_g  + (size_t)(r-768)*D; dh = wgh  + (size_t)(r-768)*D; dl = wgl  + (size_t)(r-768)*D; }
#pragma unroll
    for (int k = 0; k < 3; ++k) {
      float2 v = ((const float2*)src)[lane + 64*k];
      ushort_t h0 = f2bf(v.x), h1 = f2bf(v.y);
      ushort2 hh; hh.x = h0; hh.y = h1;
      ushort2 ll; ll.x = f2bf(v.x - bf2f(h0)); ll.y = f2bf(v.y - bf2f(h1));
      ((ushort2*)dh)[lane + 64*k] = hh;
      ((ushort2*)dl)[lane + 64*k] = ll;
    }
  }
}

// ========== sim: 2-term split-bf16 32x32x16 MFMA, BK=64, swizzled LDS ======
// 1D grid 1024; XCD-aware decode: the 8 q-tiles sharing chunk nc are
// consecutive on XCD nc%8 -> chunk read from HBM once, L2-hit 7x.
// BK=64 staged as two 32-elem column blocks -> half the barriers of BK=32.
__global__ __launch_bounds__(256, 3) void k_sim(
    const ushort_t* __restrict__ qh,
    const ushort_t* __restrict__ mh, const ushort_t* __restrict__ ml,
    const float2* __restrict__ f2a, unsigned int* __restrict__ keybuf) {
  __shared__ __align__(16) ushort_t sQh[2*4096];
  __shared__ __align__(16) ushort_t sMh[2*4096];
  __shared__ __align__(16) ushort_t sMl[2*4096];
  __shared__ __align__(16) float2 sF[CHUNK];   // per-chunk (1/mn, act+2)

  const int tid = threadIdx.x, lane = tid & 63, wave = tid >> 6;
  const int wr = wave >> 1, wc = wave & 1;
  const int l31 = lane & 31, half = lane >> 5;
  const int flat = blockIdx.x;
  const int k8 = flat & 7, qb = (flat >> 3) & 7, mgrp = flat >> 6;
  const int nc = (mgrp << 3) | k8;
  const int rowoff = lane >> 2, koff = swz_koff(lane);
  const int gsw = (l31 >> 1) & 3;          // read-side swizzle
  const size_t qrow0 = (size_t)qb * 128;

  // stage chunk stats once (coalesced): 256 x float4 = 512 float2
  ((float4*)sF)[tid] = ((const float4*)(f2a + (size_t)nc * CHUNK))[tid];

  unsigned int keys[2][3];
#pragma unroll
  for (int j = 0; j < 2; ++j) { keys[j][0] = 0; keys[j][1] = 0; keys[j][2] = 0; }

  for (int mt = 0; mt < 4; ++mt) {
    const size_t mrow0 = (size_t)nc * CHUNK + (size_t)mt * 128;
    f32x16 acc[2][2];
#pragma unroll
    for (int i = 0; i < 2; ++i)
#pragma unroll
      for (int j = 0; j < 2; ++j) acc[i][j] = (f32x16)0.0f;

    for (int kt = 0; kt < D; kt += 64) {
      __syncthreads();
      // 48 async16 stages (1 KB each) across 4 waves: arr(3) x kb(2) x slot(8)
#pragma unroll
      for (int n = 0; n < 12; ++n) {
        int f = wave*12 + n;
        int arr = f >> 4, sub = f & 15, kb = sub >> 3, slot = sub & 7;
        const ushort_t* src = arr == 0 ? qh : (arr == 1 ? mh : ml);
        ushort_t* dst = arr == 0 ? sQh : (arr == 1 ? sMh : sMl);
        size_t rowb = arr == 0 ? qrow0 : mrow0;
        async16(src + (rowb + slot*16 + rowoff)*D + kt + kb*32 + koff,
                dst + kb*4096 + slot*512 + lane*8);
      }
      __syncthreads();

#pragma unroll
      for (int kb = 0; kb < 2; ++kb) {
        const int base = kb*4096;
        bf16x8 ah[2][2], al[2][2], bh[2][2];
#pragma unroll
        for (int i = 0; i < 2; ++i)
#pragma unroll
          for (int s = 0; s < 2; ++s) {
            int gra = ((s*2 + half) ^ gsw) * 8;
            int ro = base + (wr*64 + i*32 + l31)*32 + gra;
            ah[i][s] = *(const bf16x8*)&sMh[ro];
            al[i][s] = *(const bf16x8*)&sMl[ro];
            int co = base + (wc*64 + i*32 + l31)*32 + gra;
            bh[i][s] = *(const bf16x8*)&sQh[co];
          }
#pragma unroll
        for (int i = 0; i < 2; ++i)
#pragma unroll
          for (int j = 0; j < 2; ++j)
#pragma unroll
            for (int s = 0; s < 2; ++s) {
              acc[i][j] = __builtin_amdgcn_mfma_f32_32x32x16_bf16(ah[i][s], bh[j][s], acc[i][j], 0, 0, 0);
              acc[i][j] = __builtin_amdgcn_mfma_f32_32x32x16_bf16(al[i][s], bh[j][s], acc[i][j], 0, 0, 0);
            }
      }
    }

    // epilogue: C layout col=lane&31, row=(r&3)+8*(r>>2)+4*half; stats from LDS
#pragma unroll
    for (int i = 0; i < 2; ++i)
#pragma unroll
      for (int rg = 0; rg < 4; ++rg)
#pragma unroll
        for (int rr = 0; rr < 4; ++rr) {
          int rl = wr*64 + i*32 + half*4 + rr + 8*rg;
          float2 fa = sF[mt*128 + rl];
          unsigned int idx = (unsigned int)(((nc & 1) << 9) | (mt*128 + rl));
          float v0 = fmaf(acc[i][0][rg*4+rr], fa.x, fa.y);
          insert3b(keys[0], (__float_as_uint(v0) & 0xFFFFFC00u) | idx);
          float v1 = fmaf(acc[i][1][rg*4+rr], fa.x, fa.y);
          insert3b(keys[1], (__float_as_uint(v1) & 0xFFFFFC00u) | idx);
        }
  }

#pragma unroll
  for (int j = 0; j < 2; ++j) {
    int q_local = wc*64 + j*32 + l31;
    int c = wr*2 + half;
    size_t off = ((size_t)(qb*128 + q_local) * NC + nc) * 12 + c*3;
    keybuf[off+0] = keys[j][0];
    keybuf[off+1] = keys[j][1];
    keybuf[off+2] = keys[j][2];
  }
}

// ===== merge: block per query; wave0 tournament, 4-way parallel rescore =====
__global__ __launch_bounds__(256) void k_merge(
    const unsigned int* __restrict__ keybuf,
    const float* __restrict__ query, const float* __restrict__ memv,
    const float2* __restrict__ f2b, int* __restrict__ topk) {
  __shared__ int sCand[16];
  __shared__ float sSimv[16];
  const int tid = threadIdx.x, lane = tid & 63, wave = tid >> 6;
  const int q = blockIdx.x;

  if (wave == 0) {
    // lane covers chunks 2*lane, 2*lane+1: 24 contiguous keys
    const unsigned int* kb = keybuf + (size_t)q * (NC*12) + (size_t)lane * 24;
    unsigned int k5[5] = {0,0,0,0,0};
#pragma unroll
    for (int c = 0; c < 6; ++c) {
      uint4 v = *(const uint4*)(kb + c*4);
      insert5b(k5, v.x); insert5b(k5, v.y); insert5b(k5, v.z); insert5b(k5, v.w);
    }
#pragma unroll
    for (int p = 0; p < 16; ++p) {
      unsigned int bk = k5[0]; int blv = lane;
#pragma unroll
      for (int off = 1; off < 64; off <<= 1) {
        unsigned int ok = (unsigned int)__shfl_xor((int)bk, off);
        int ol = __shfl_xor(blv, off);
        if (ok > bk || (ok == bk && ol < blv)) { bk = ok; blv = ol; }
      }
      if (lane == blv) { k5[0]=k5[1]; k5[1]=k5[2]; k5[2]=k5[3]; k5[3]=k5[4]; k5[4]=0; }
      if (lane == 0) sCand[p] = (blv << 10) | (int)(bk & 1023u);
    }
  }
  __syncthreads();

  // each wave rescores 4 candidates in exact fp32
  float qv[6]; float sq = 0.f;
#pragma unroll
  for (int k = 0; k < 6; ++k) { qv[k] = query[(size_t)q*D + lane + 64*k]; sq += qv[k]*qv[k]; }
#pragma unroll
  for (int o = 32; o > 0; o >>= 1) sq += __shfl_xor(sq, o);
  float qn = sqrtf(sq);

#pragma unroll
  for (int pp = 0; pp < 4; ++pp) {
    int p = wave*4 + pp;
    int mi = sCand[p];
    float d = 0.f;
#pragma unroll
    for (int k = 0; k < 6; ++k) d += qv[k] * memv[(size_t)mi*D + lane + 64*k];
#pragma unroll
    for (int o = 32; o > 0; o >>= 1) d += __shfl_xor(d, o);
    if (lane == 0) {
      float2 fb = f2b[mi];
      sSimv[p] = d / fmaxf(qn * fb.x, FEPS) + fb.y;
    }
  }
  __syncthreads();

  if (tid == 0) {
    float cv[16]; int ci[16];
#pragma unroll
    for (int p = 0; p < 16; ++p) { cv[p] = sSimv[p]; ci[p] = sCand[p]; }
    for (int s = 0; s < KK; ++s) {
      int best = -1; float bv = -1e30f; int bi = 0x7FFFFFFF;
      for (int p = 0; p < 16; ++p) {
        if (ci[p] < 0) continue;
        if (cv[p] > bv || (cv[p] == bv && ci[p] < bi)) { best = p; bv = cv[p]; bi = ci[p]; }
      }
      topk[q*KK + s] = ci[best];
      ci[best] = -1;
    }
  }
}

// ===== tail1: x_proj (gathered, 96 row-tiles) + gate (16 row-tiles) + h1 ====
// grid (112, 6); 64x64 tile, K=384 in 3 rounds of 4x32 subtiles; 3-term split
__global__ __launch_bounds__(256) void k_tail1(
    const ushort_t* __restrict__ qrh, const ushort_t* __restrict__ qrl,
    const ushort_t* __restrict__ mh, const ushort_t* __restrict__ ml,
    const int* __restrict__ topk,
    const ushort_t* __restrict__ wihh, const ushort_t* __restrict__ wihl,
    const ushort_t* __restrict__ wgh, const ushort_t* __restrict__ wgl,
    const float* __restrict__ b_ih, const float* __restrict__ b_hh,
    const float* __restrict__ b_g,
    float* __restrict__ xp, float* __restrict__ gate,
    ushort_t* __restrict__ hoh, ushort_t* __restrict__ hol) {
  __shared__ __align__(16) ushort_t sAh[64*128];
  __shared__ __align__(16) ushort_t sAl[64*128];
  __shared__ __align__(16) ushort_t sWh[64*128];
  __shared__ __align__(16) ushort_t sWl[64*128];

  const int tid = threadIdx.x, lane = tid & 63, wave = tid >> 6;
  const int wr = wave >> 1, wc = wave & 1;
  const int t = lane & 15, quad = lane >> 4;
  const bool xmode = blockIdx.x < 96;
  const int cbase = blockIdx.y * 64;
  const int rowoff = lane >> 2, koff = swz_koff(lane);
  const int pq = (quad ^ ((t >> 1) & 3)) * 8;    // swizzled read granule

  const ushort_t* gp[4];
  if (wave < 2) {
#pragma unroll
    for (int slot = 0; slot < 4; ++slot) {
      int rl = slot*16 + rowoff;
      const ushort_t* src;
      if (xmode) {
        int g = blockIdx.x*64 + rl;
        int b = g / 6, tt = g - b*6;
        if (tt == 0) src = (wave == 0 ? qrh : qrl) + (size_t)b * D;
        else         src = (wave == 0 ? mh  : ml ) + (size_t)topk[b*KK + tt - 1] * D;
      } else {
        int rq = (blockIdx.x - 96)*64 + rl;
        src = (wave == 0 ? qrh : qrl) + (size_t)rq * D;
      }
      gp[slot] = src + koff;
    }
  } else {
#pragma unroll
    for (int slot = 0; slot < 4; ++slot) {
      int rl = slot*16 + rowoff;
      const ushort_t* wsrc = xmode ? (wave == 2 ? wihh : wihl)
                                   : (wave == 2 ? wgh  : wgl);
      gp[slot] = wsrc + (size_t)(cbase + rl) * D + koff;
    }
  }
  ushort_t* ldst = (wave == 0) ? sAh : (wave == 1) ? sAl : (wave == 2) ? sWh : sWl;

  f32x4 acc[2][2];
#pragma unroll
  for (int i = 0; i < 2; ++i)
#pragma unroll
    for (int j = 0; j < 2; ++j) acc[i][j] = (f32x4)0.0f;

  for (int r3 = 0; r3 < 3; ++r3) {
    __syncthreads();
#pragma unroll
    for (int s = 0; s < 4; ++s)
#pragma unroll
      for (int slot = 0; slot < 4; ++slot)
        async16(gp[slot] + r3*128 + s*32, ldst + s*2048 + slot*512 + lane*8);
    __syncthreads();
#pragma unroll
    for (int s = 0; s < 4; ++s) {
      bf16x8 ah[2], al[2], bh[2], bl[2];
#pragma unroll
      for (int i = 0; i < 2; ++i) {
        int ro = s*2048 + (wr*32 + i*16 + t)*32 + pq;
        ah[i] = *(const bf16x8*)&sAh[ro];
        al[i] = *(const bf16x8*)&sAl[ro];
        int co = s*2048 + (wc*32 + i*16 + t)*32 + pq;
        bh[i] = *(const bf16x8*)&sWh[co];
        bl[i] = *(const bf16x8*)&sWl[co];
      }
#pragma unroll
      for (int i = 0; i < 2; ++i)
#pragma unroll
        for (int j = 0; j < 2; ++j) {
          acc[i][j] = __builtin_amdgcn_mfma_f32_16x16x32_bf16(ah[i], bh[j], acc[i][j], 0, 0, 0);
          acc[i][j] = __builtin_amdgcn_mfma_f32_16x16x32_bf16(ah[i], bl[j], acc[i][j], 0, 0, 0);
          acc[i][j] = __builtin_amdgcn_mfma_f32_16x16x32_bf16(al[i], bh[j], acc[i][j], 0, 0, 0);
        }
    }
  }

#pragma unroll
  for (int i = 0; i < 2; ++i)
#pragma unroll
    for (int j = 0; j < 2; ++j)
#pragma unroll
      for (int r = 0; r < 4; ++r) {
        int rloc = wr*32 + i*16 + quad*4 + r;
        int h = cbase + wc*32 + j*16 + t;
        float a = acc[i][j][r];
        if (xmode) {
          int g = blockIdx.x*64 + rloc;
          float v = a + b_ih[h];
          xp[(size_t)g*H + h] = v;
          int b = g / 6;
          if (g - b*6 == 0) {
            float hv = tanhf(v + b_hh[h]);
            ushort_t hi = f2bf(hv);
            hoh[(size_t)b*H + h] = hi;
            hol[(size_t)b*H + h] = f2bf(hv - bf2f(hi));
          }
        } else {
          int rq = (blockIdx.x - 96)*64 + rloc;
          gate[(size_t)rq*H + h] = 1.0f / (1.0f + expf(-(a + b_g[h])));
        }
      }
}

// ================= RNN step: h' = tanh(x_t + h @ W_hh^T + b_hh) =============
// grid (16, 6); LAST fuses the gated output blend
template<int LAST>
__global__ __launch_bounds__(256) void k_rnn(
    const ushort_t* __restrict__ hih, const ushort_t* __restrict__ hil,
    const ushort_t* __restrict__ whhh, const ushort_t* __restrict__ whhl,
    const float* __restrict__ b_hh, const float* __restrict__ xp,
    const float* __restrict__ gate, int step,
    ushort_t* __restrict__ hoh, ushort_t* __restrict__ hol,
    float* __restrict__ out) {
  __shared__ __align__(16) ushort_t sAh[64*128];
  __shared__ __align__(16) ushort_t sAl[64*128];
  __shared__ __align__(16) ushort_t sWh[64*128];
  __shared__ __align__(16) ushort_t sWl[64*128];

  const int tid = threadIdx.x, lane = tid & 63, wave = tid >> 6;
  const int wr = wave >> 1, wc = wave & 1;
  const int t = lane & 15, quad = lane >> 4;
  const int rbase = blockIdx.x * 64, cbase = blockIdx.y * 64;
  const int rowoff = lane >> 2, koff = swz_koff(lane);
  const int pq = (quad ^ ((t >> 1) & 3)) * 8;

  const ushort_t* gp[4];
#pragma unroll
  for (int slot = 0; slot < 4; ++slot) {
    int rl = slot*16 + rowoff;
    const ushort_t* src =
        (wave == 0) ? hih + (size_t)(rbase + rl)*D :
        (wave == 1) ? hil + (size_t)(rbase + rl)*D :
        (wave == 2) ? whhh + (size_t)(cbase + rl)*D :
                      whhl + (size_t)(cbase + rl)*D;
    gp[slot] = src + koff;
  }
  ushort_t* ldst = (wave == 0) ? sAh : (wave == 1) ? sAl : (wave == 2) ? sWh : sWl;

  f32x4 acc[2][2];
#pragma unroll
  for (int i = 0; i < 2; ++i)
#pragma unroll
    for (int j = 0; j < 2; ++j) acc[i][j] = (f32x4)0.0f;

  for (int r3 = 0; r3 < 3; ++r3) {
    __syncthreads();
#pragma unroll
    for (int s = 0; s < 4; ++s)
#pragma unroll
      for (int slot = 0; slot < 4; ++slot)
        async16(gp[slot] + r3*128 + s*32, ldst + s*2048 + slot*512 + lane*8);
    __syncthreads();
#pragma unroll
    for (int s = 0; s < 4; ++s) {
      bf16x8 ah[2], al[2], bh[2], bl[2];
#pragma unroll
      for (int i = 0; i < 2; ++i) {
        int ro = s*2048 + (wr*32 + i*16 + t)*32 + pq;
        ah[i] = *(const bf16x8*)&sAh[ro];
        al[i] = *(const bf16x8*)&sAl[ro];
        int co = s*2048 + (wc*32 + i*16 + t)*32 + pq;
        bh[i] = *(const bf16x8*)&sWh[co];
        bl[i] = *(const bf16x8*)&sWl[co];
      }
#pragma unroll
      for (int i = 0; i < 2; ++i)
#pragma unroll
        for (int j = 0; j < 2; ++j) {
          acc[i][j] = __builtin_amdgcn_mfma_f32_16x16x32_bf16(ah[i], bh[j], acc[i][j], 0, 0, 0);
          acc[i][j] = __builtin_amdgcn_mfma_f32_16x16x32_bf16(ah[i], bl[j], acc[i][j], 0, 0, 0);
          acc[i][j] = __builtin_amdgcn_mfma_f32_16x16x32_bf16(al[i], bh[j], acc[i][j], 0, 0, 0);
        }
    }
  }

#pragma unroll
  for (int i = 0; i < 2; ++i)
#pragma unroll
    for (int j = 0; j < 2; ++j)
#pragma unroll
      for (int r = 0; r < 4; ++r) {
        int row = rbase + wr*32 + i*16 + quad*4 + r;
        int h = cbase + wc*32 + j*16 + t;
        float v = acc[i][j][r] + b_hh[h] + xp[(size_t)row*(6*H) + step*H + h];
        float hv = tanhf(v);
        if (LAST) {
          float g = gate[(size_t)row*H + h];
          out[(size_t)row*H + h] = g*hv + (1.0f - g)*xp[(size_t)row*(6*H) + h];
        } else {
          ushort_t hi = f2bf(hv);
          hoh[(size_t)row*H + h] = hi;
          hol[(size_t)row*H + h] = f2bf(hv - bf2f(hi));
        }
      }
}

} // namespace

extern "C" void kernel_launch(void* const* d_in, const int* in_sizes, int n_in,
                              void* d_out, int out_size, void* d_ws, size_t ws_size,
                              hipStream_t stream) {
  const float* query = (const float*)d_in[0];
  const float* memv  = (const float*)d_in[1];
  const float* coords= (const float*)d_in[2];
  const float* sw    = (const float*)d_in[3];
  const float* W_ih  = (const float*)d_in[4];
  const float* b_ih  = (const float*)d_in[5];
  const float* W_hh  = (const float*)d_in[6];
  const float* b_hh  = (const float*)d_in[7];
  const float* W_g   = (const float*)d_in[8];
  const float* b_g   = (const float*)d_in[9];
  float* out = (float*)d_out;

  char* p = (char*)d_ws;
  auto alloc = [&](size_t bytes) {
    char* r = p; p += (bytes + 255) & ~(size_t)255; return r;
  };
  ushort_t* qh  = (ushort_t*)alloc((size_t)B * D * 2);
  ushort_t* qrh = (ushort_t*)alloc((size_t)B * D * 2);
  ushort_t* qrl = (ushort_t*)alloc((size_t)B * D * 2);
  ushort_t* mh  = (ushort_t*)alloc((size_t)M * D * 2);
  ushort_t* ml  = (ushort_t*)alloc((size_t)M * D * 2);
  float2* f2a   = (float2*)alloc((size_t)M * 8);
  float2* f2b   = (float2*)alloc((size_t)M * 8);
  ushort_t* wihh = (ushort_t*)alloc((size_t)H * D * 2);
  ushort_t* wihl = (ushort_t*)alloc((size_t)H * D * 2);
  ushort_t* whhh = (ushort_t*)alloc((size_t)H * D * 2);
  ushort_t* whhl = (ushort_t*)alloc((size_t)H * D * 2);
  ushort_t* wgh  = (ushort_t*)alloc((size_t)H * D * 2);
  ushort_t* wgl  = (ushort_t*)alloc((size_t)H * D * 2);
  unsigned int* keybuf = (unsigned int*)alloc((size_t)B * NC * 12 * 4);
  int*   topk   = (int*)alloc((size_t)B * KK * 4);
  float* xp     = (float*)alloc((size_t)B * 6 * H * 4);
  float* gate   = (float*)alloc((size_t)B * H * 4);
  ushort_t* hAh = (ushort_t*)alloc((size_t)B * H * 2);
  ushort_t* hAl = (ushort_t*)alloc((size_t)B * H * 2);
  ushort_t* hBh = (ushort_t*)alloc((size_t)B * H * 2);
  ushort_t* hBl = (ushort_t*)alloc((size_t)B * H * 2);

  k_prep<<<M/4 + B/4 + 288, 256, 0, stream>>>(
      query, memv, coords, sw, W_ih, W_hh, W_g,
      qh, qrh, qrl, mh, ml, f2a, f2b,
      wihh, wihl, whhh, whhl, wgh, wgl);
  k_sim<<<1024, 256, 0, stream>>>(qh, mh, ml, f2a, keybuf);
  k_merge<<<B, 256, 0, stream>>>(keybuf, query, memv, f2b, topk);
  k_tail1<<<dim3(112, 6), 256, 0, stream>>>(
      qrh, qrl, mh, ml, topk, wihh, wihl, wgh, wgl,
      b_ih, b_hh, b_g, xp, gate, hAh, hAl);
  k_rnn<0><<<dim3(16, 6), 256, 0, stream>>>(hAh, hAl, whhh, whhl, b_hh, xp, gate, 1, hBh, hBl, out);
  k_rnn<0><<<dim3(16, 6), 256, 0, stream>>>(hBh, hBl, whhh, whhl, b_hh, xp, gate, 2, hAh, hAl, out);
  k_rnn<0><<<dim3(16, 6), 256, 0, stream>>>(hAh, hAl, whhh, whhl, b_hh, xp, gate, 3, hBh, hBl, out);
  k_rnn<0><<<dim3(16, 6), 256, 0, stream>>>(hBh, hBl, whhh, whhl, b_hh, xp, gate, 4, hAh, hAl, out);
  k_rnn<1><<<dim3(16, 6), 256, 0, stream>>>(hAh, hAl, whhh, whhl, b_hh, xp, gate, 5, hBh, hBl, out);
}

// Round 8
// 363.435 us; speedup vs baseline: 1.4180x; 1.1267x over previous
//
#include <hip/hip_runtime.h>
#include <math.h>

namespace {

typedef float f32x4 __attribute__((ext_vector_type(4)));
typedef float f32x16 __attribute__((ext_vector_type(16)));
typedef short bf16x8 __attribute__((ext_vector_type(8)));
typedef unsigned short ushort_t;

constexpr int B  = 1024;
constexpr int M  = 65536;
constexpr int D  = 384;
constexpr int H  = 384;
constexpr int KK = 5;
constexpr int NC = 128;         // chunks over M
constexpr int CHUNK = M / NC;   // 512 mems per chunk
constexpr float FEPS = 1e-8f;

__device__ __forceinline__ ushort_t f2bf(float x) {
  unsigned int u = __float_as_uint(x);
  unsigned int r = (u + 0x7FFFu + ((u >> 16) & 1u)) >> 16;   // RNE
  return (ushort_t)r;
}
__device__ __forceinline__ float bf2f(ushort_t h) {
  return __uint_as_float(((unsigned int)h) << 16);
}

__device__ __forceinline__ void async16(const ushort_t* g, ushort_t* l) {
  __builtin_amdgcn_global_load_lds(
      (const __attribute__((address_space(1))) unsigned int*)g,
      (__attribute__((address_space(3))) unsigned int*)l, 16, 0, 0);
}

__device__ __forceinline__ void insert3b(unsigned int* k, unsigned int v) {
  unsigned int t0 = min(k[0], v); k[0] = max(k[0], v);
  unsigned int t1 = min(k[1], t0); k[1] = max(k[1], t0);
  k[2] = max(k[2], t1);
}
__device__ __forceinline__ void insert5b(unsigned int* k, unsigned int v) {
  unsigned int t0 = min(k[0], v); k[0] = max(k[0], v);
  unsigned int t1 = min(k[1], t0); k[1] = max(k[1], t0);
  unsigned int t2 = min(k[2], t1); k[2] = max(k[2], t1);
  unsigned int t3 = min(k[3], t2); k[3] = max(k[3], t2);
  k[4] = max(k[4], t3);
}

// swizzled per-lane global k-offset for staging: LDS granule (lane&3) of row
// (lane>>2) holds logical granule (lane&3) ^ ((row>>1)&3).  [bank-conflict fix]
__device__ __forceinline__ int swz_koff(int lane) {
  return (((lane & 3) ^ ((lane >> 3) & 3)) * 8);
}

// ================= mega prep: mem split+stats | q splits | weight splits ====
// lane handles 2 consecutive elements: float2 reads, ushort2 writes
__global__ __launch_bounds__(256) void k_prep(
    const float* __restrict__ q, const float* __restrict__ mem,
    const float* __restrict__ coords, const float* __restrict__ sw,
    const float* __restrict__ W_ih, const float* __restrict__ W_hh,
    const float* __restrict__ W_g,
    ushort_t* __restrict__ qh, ushort_t* __restrict__ qrh, ushort_t* __restrict__ qrl,
    ushort_t* __restrict__ mh, ushort_t* __restrict__ ml,
    float2* __restrict__ f2a, float2* __restrict__ f2b,
    ushort_t* __restrict__ wihh, ushort_t* __restrict__ wihl,
    ushort_t* __restrict__ whhh, ushort_t* __restrict__ whhl,
    ushort_t* __restrict__ wgh, ushort_t* __restrict__ wgl) {
  int wv = threadIdx.x >> 6, lane = threadIdx.x & 63;
  int bid = blockIdx.x;
  if (bid < M/4) {
    int r = bid*4 + wv;
    float cx = 0.f, cy = 0.f;
    for (int i = lane; i < H; i += 64) { cx += sw[2*i]; cy += sw[2*i+1]; }
#pragma unroll
    for (int o = 32; o > 0; o >>= 1) { cx += __shfl_xor(cx, o); cy += __shfl_xor(cy, o); }
    cx *= (1.0f/384.0f); cy *= (1.0f/384.0f);
    float2 x[3]; float s = 0.f;
#pragma unroll
    for (int k = 0; k < 3; ++k) {
      x[k] = ((const float2*)(mem + (size_t)r*D))[lane + 64*k];
      s += x[k].x*x[k].x + x[k].y*x[k].y;
    }
#pragma unroll
    for (int o = 32; o > 0; o >>= 1) s += __shfl_xor(s, o);
#pragma unroll
    for (int k = 0; k < 3; ++k) {
      ushort_t h0 = f2bf(x[k].x), h1 = f2bf(x[k].y);
      ushort2 hh; hh.x = h0; hh.y = h1;
      ushort2 ll; ll.x = f2bf(x[k].x - bf2f(h0)); ll.y = f2bf(x[k].y - bf2f(h1));
      ((ushort2*)(mh + (size_t)r*D))[lane + 64*k] = hh;
      ((ushort2*)(ml + (size_t)r*D))[lane + 64*k] = ll;
    }
    if (lane == 0) {
      float mn = sqrtf(s);
      float dx = coords[2*r] - cx, dy = coords[2*r+1] - cy;
      float act = 1.0f / (1.0f + sqrtf(dx*dx + dy*dy));
      f2a[r] = make_float2(1.0f / mn, act + 2.0f);
      f2b[r] = make_float2(mn, act);
    }
  } else if (bid < M/4 + B/4) {
    int r = (bid - M/4)*4 + wv;
    float2 x[3]; float s = 0.f;
#pragma unroll
    for (int k = 0; k < 3; ++k) {
      x[k] = ((const float2*)(q + (size_t)r*D))[lane + 64*k];
      s += x[k].x*x[k].x + x[k].y*x[k].y;
    }
#pragma unroll
    for (int o = 32; o > 0; o >>= 1) s += __shfl_xor(s, o);
    float inv = 1.0f / sqrtf(s);
#pragma unroll
    for (int k = 0; k < 3; ++k) {
      ushort_t h0 = f2bf(x[k].x), h1 = f2bf(x[k].y);
      ushort2 hh; hh.x = h0; hh.y = h1;
      ushort2 ll; ll.x = f2bf(x[k].x - bf2f(h0)); ll.y = f2bf(x[k].y - bf2f(h1));
      ((ushort2*)(qrh + (size_t)r*D))[lane + 64*k] = hh;
      ((ushort2*)(qrl + (size_t)r*D))[lane + 64*k] = ll;
      ushort2 nn; nn.x = f2bf(x[k].x * inv); nn.y = f2bf(x[k].y * inv);
      ((ushort2*)(qh + (size_t)r*D))[lane + 64*k] = nn;
    }
  } else {
    int r = (bid - M/4 - B/4)*4 + wv;   // 0..1151
    const float* src; ushort_t* dh; ushort_t* dl;
    if (r < 384)      { src = W_ih + (size_t)r*D;       dh = wihh + (size_t)r*D;       dl = wihl + (size_t)r*D; }
    else if (r < 768) { src = W_hh + (size_t)(r-384)*D; dh = whhh + (size_t)(r-384)*D; dl = whhl + (size_t)(r-384)*D; }
    else              { src = W_g  + (size_t)(r-768)*D; dh = wgh  + (size_t)(r-768)*D; dl = wgl  + (size_t)(r-768)*D; }
#pragma unroll
    for (int k = 0; k < 3; ++k) {
      float2 v = ((const float2*)src)[lane + 64*k];
      ushort_t h0 = f2bf(v.x), h1 = f2bf(v.y);
      ushort2 hh; hh.x = h0; hh.y = h1;
      ushort2 ll; ll.x = f2bf(v.x - bf2f(h0)); ll.y = f2bf(v.y - bf2f(h1));
      ((ushort2*)dh)[lane + 64*k] = hh;
      ((ushort2*)dl)[lane + 64*k] = ll;
    }
  }
}

// ========== sim: 1-term mh x qh 32x32x16 MFMA, BK=32, swizzled LDS =========
// 1D grid 1024; XCD-aware decode: the 8 q-tiles sharing chunk nc are
// consecutive on XCD nc%8 -> chunk read from HBM once, L2-hit 7x.
// m-side lo term dropped: noise ~5.6e-5 << key quantization 2.4e-4, and the
// 16-candidate exact-fp32 rescore makes ranking robust to it.
__global__ __launch_bounds__(256, 2) void k_sim(
    const ushort_t* __restrict__ qh,
    const ushort_t* __restrict__ mh,
    const float2* __restrict__ f2a, unsigned int* __restrict__ keybuf) {
  __shared__ __align__(16) ushort_t sQh[128*32];
  __shared__ __align__(16) ushort_t sMh[128*32];
  __shared__ __align__(16) float2 sF[CHUNK];   // per-chunk (1/mn, act+2)

  const int tid = threadIdx.x, lane = tid & 63, wave = tid >> 6;
  const int wr = wave >> 1, wc = wave & 1;
  const int l31 = lane & 31, half = lane >> 5;
  const int flat = blockIdx.x;
  const int k8 = flat & 7, qb = (flat >> 3) & 7, mgrp = flat >> 6;
  const int nc = (mgrp << 3) | k8;
  const int rowoff = lane >> 2, koff = swz_koff(lane);
  const int gsw = (l31 >> 1) & 3;          // read-side swizzle
  const size_t qrow0 = (size_t)qb * 128;

  // stage chunk stats once (coalesced): 256 x float4 = 512 float2
  ((float4*)sF)[tid] = ((const float4*)(f2a + (size_t)nc * CHUNK))[tid];

  unsigned int keys[2][3];
#pragma unroll
  for (int j = 0; j < 2; ++j) { keys[j][0] = 0; keys[j][1] = 0; keys[j][2] = 0; }

  for (int mt = 0; mt < 4; ++mt) {
    const size_t mrow0 = (size_t)nc * CHUNK + (size_t)mt * 128;
    f32x16 acc[2][2];
#pragma unroll
    for (int i = 0; i < 2; ++i)
#pragma unroll
      for (int j = 0; j < 2; ++j) acc[i][j] = (f32x16)0.0f;

    for (int kt = 0; kt < D; kt += 32) {
      __syncthreads();
      // 16 async16 stages across 4 waves: arr(2: qh,mh) x slot(8)
#pragma unroll
      for (int n = 0; n < 4; ++n) {
        int f = wave*4 + n; int arr = f >> 3, slot = f & 7;
        const ushort_t* src = arr == 0 ? qh : mh;
        ushort_t* dst = arr == 0 ? sQh : sMh;
        size_t rowb = arr == 0 ? qrow0 : mrow0;
        async16(src + (rowb + slot*16 + rowoff)*D + kt + koff,
                dst + slot*512 + lane*8);
      }
      __syncthreads();

      bf16x8 ah[2][2], bh[2][2];
#pragma unroll
      for (int i = 0; i < 2; ++i)
#pragma unroll
        for (int s = 0; s < 2; ++s) {
          int gra = ((s*2 + half) ^ gsw) * 8;
          int ro = (wr*64 + i*32 + l31)*32 + gra;
          ah[i][s] = *(const bf16x8*)&sMh[ro];
          int co = (wc*64 + i*32 + l31)*32 + gra;
          bh[i][s] = *(const bf16x8*)&sQh[co];
        }
#pragma unroll
      for (int i = 0; i < 2; ++i)
#pragma unroll
        for (int j = 0; j < 2; ++j)
#pragma unroll
          for (int s = 0; s < 2; ++s)
            acc[i][j] = __builtin_amdgcn_mfma_f32_32x32x16_bf16(ah[i][s], bh[j][s], acc[i][j], 0, 0, 0);
    }

    // epilogue: C layout col=lane&31, row=(r&3)+8*(r>>2)+4*half; stats from LDS
#pragma unroll
    for (int i = 0; i < 2; ++i)
#pragma unroll
      for (int rg = 0; rg < 4; ++rg)
#pragma unroll
        for (int rr = 0; rr < 4; ++rr) {
          int rl = wr*64 + i*32 + half*4 + rr + 8*rg;
          float2 fa = sF[mt*128 + rl];
          unsigned int idx = (unsigned int)(((nc & 1) << 9) | (mt*128 + rl));
          float v0 = fmaf(acc[i][0][rg*4+rr], fa.x, fa.y);
          insert3b(keys[0], (__float_as_uint(v0) & 0xFFFFFC00u) | idx);
          float v1 = fmaf(acc[i][1][rg*4+rr], fa.x, fa.y);
          insert3b(keys[1], (__float_as_uint(v1) & 0xFFFFFC00u) | idx);
        }
  }

#pragma unroll
  for (int j = 0; j < 2; ++j) {
    int q_local = wc*64 + j*32 + l31;
    int c = wr*2 + half;
    size_t off = ((size_t)(qb*128 + q_local) * NC + nc) * 12 + c*3;
    keybuf[off+0] = keys[j][0];
    keybuf[off+1] = keys[j][1];
    keybuf[off+2] = keys[j][2];
  }
}

// ===== merge: block per query; wave0 tournament, 4-way parallel rescore =====
__global__ __launch_bounds__(256) void k_merge(
    const unsigned int* __restrict__ keybuf,
    const float* __restrict__ query, const float* __restrict__ memv,
    const float2* __restrict__ f2b, int* __restrict__ topk) {
  __shared__ int sCand[16];
  __shared__ float sSimv[16];
  const int tid = threadIdx.x, lane = tid & 63, wave = tid >> 6;
  const int q = blockIdx.x;

  if (wave == 0) {
    // lane covers chunks 2*lane, 2*lane+1: 24 contiguous keys
    const unsigned int* kb = keybuf + (size_t)q * (NC*12) + (size_t)lane * 24;
    unsigned int k5[5] = {0,0,0,0,0};
#pragma unroll
    for (int c = 0; c < 6; ++c) {
      uint4 v = *(const uint4*)(kb + c*4);
      insert5b(k5, v.x); insert5b(k5, v.y); insert5b(k5, v.z); insert5b(k5, v.w);
    }
#pragma unroll
    for (int p = 0; p < 16; ++p) {
      unsigned int bk = k5[0]; int blv = lane;
#pragma unroll
      for (int off = 1; off < 64; off <<= 1) {
        unsigned int ok = (unsigned int)__shfl_xor((int)bk, off);
        int ol = __shfl_xor(blv, off);
        if (ok > bk || (ok == bk && ol < blv)) { bk = ok; blv = ol; }
      }
      if (lane == blv) { k5[0]=k5[1]; k5[1]=k5[2]; k5[2]=k5[3]; k5[3]=k5[4]; k5[4]=0; }
      if (lane == 0) sCand[p] = (blv << 10) | (int)(bk & 1023u);
    }
  }
  __syncthreads();

  // each wave rescores 4 candidates in exact fp32
  float qv[6]; float sq = 0.f;
#pragma unroll
  for (int k = 0; k < 6; ++k) { qv[k] = query[(size_t)q*D + lane + 64*k]; sq += qv[k]*qv[k]; }
#pragma unroll
  for (int o = 32; o > 0; o >>= 1) sq += __shfl_xor(sq, o);
  float qn = sqrtf(sq);

#pragma unroll
  for (int pp = 0; pp < 4; ++pp) {
    int p = wave*4 + pp;
    int mi = sCand[p];
    float d = 0.f;
#pragma unroll
    for (int k = 0; k < 6; ++k) d += qv[k] * memv[(size_t)mi*D + lane + 64*k];
#pragma unroll
    for (int o = 32; o > 0; o >>= 1) d += __shfl_xor(d, o);
    if (lane == 0) {
      float2 fb = f2b[mi];
      sSimv[p] = d / fmaxf(qn * fb.x, FEPS) + fb.y;
    }
  }
  __syncthreads();

  if (tid == 0) {
    float cv[16]; int ci[16];
#pragma unroll
    for (int p = 0; p < 16; ++p) { cv[p] = sSimv[p]; ci[p] = sCand[p]; }
    for (int s = 0; s < KK; ++s) {
      int best = -1; float bv = -1e30f; int bi = 0x7FFFFFFF;
      for (int p = 0; p < 16; ++p) {
        if (ci[p] < 0) continue;
        if (cv[p] > bv || (cv[p] == bv && ci[p] < bi)) { best = p; bv = cv[p]; bi = ci[p]; }
      }
      topk[q*KK + s] = ci[best];
      ci[best] = -1;
    }
  }
}

// ===== tail1: x_proj (gathered, 96 row-tiles) + gate (16 row-tiles) + h1 ====
// grid (112, 6); 64x64 tile, K=384 in 3 rounds of 4x32 subtiles; 3-term split
__global__ __launch_bounds__(256) void k_tail1(
    const ushort_t* __restrict__ qrh, const ushort_t* __restrict__ qrl,
    const ushort_t* __restrict__ mh, const ushort_t* __restrict__ ml,
    const int* __restrict__ topk,
    const ushort_t* __restrict__ wihh, const ushort_t* __restrict__ wihl,
    const ushort_t* __restrict__ wgh, const ushort_t* __restrict__ wgl,
    const float* __restrict__ b_ih, const float* __restrict__ b_hh,
    const float* __restrict__ b_g,
    float* __restrict__ xp, float* __restrict__ gate,
    ushort_t* __restrict__ hoh, ushort_t* __restrict__ hol) {
  __shared__ __align__(16) ushort_t sAh[64*128];
  __shared__ __align__(16) ushort_t sAl[64*128];
  __shared__ __align__(16) ushort_t sWh[64*128];
  __shared__ __align__(16) ushort_t sWl[64*128];

  const int tid = threadIdx.x, lane = tid & 63, wave = tid >> 6;
  const int wr = wave >> 1, wc = wave & 1;
  const int t = lane & 15, quad = lane >> 4;
  const bool xmode = blockIdx.x < 96;
  const int cbase = blockIdx.y * 64;
  const int rowoff = lane >> 2, koff = swz_koff(lane);
  const int pq = (quad ^ ((t >> 1) & 3)) * 8;    // swizzled read granule

  const ushort_t* gp[4];
  if (wave < 2) {
#pragma unroll
    for (int slot = 0; slot < 4; ++slot) {
      int rl = slot*16 + rowoff;
      const ushort_t* src;
      if (xmode) {
        int g = blockIdx.x*64 + rl;
        int b = g / 6, tt = g - b*6;
        if (tt == 0) src = (wave == 0 ? qrh : qrl) + (size_t)b * D;
        else         src = (wave == 0 ? mh  : ml ) + (size_t)topk[b*KK + tt - 1] * D;
      } else {
        int rq = (blockIdx.x - 96)*64 + rl;
        src = (wave == 0 ? qrh : qrl) + (size_t)rq * D;
      }
      gp[slot] = src + koff;
    }
  } else {
#pragma unroll
    for (int slot = 0; slot < 4; ++slot) {
      int rl = slot*16 + rowoff;
      const ushort_t* wsrc = xmode ? (wave == 2 ? wihh : wihl)
                                   : (wave == 2 ? wgh  : wgl);
      gp[slot] = wsrc + (size_t)(cbase + rl) * D + koff;
    }
  }
  ushort_t* ldst = (wave == 0) ? sAh : (wave == 1) ? sAl : (wave == 2) ? sWh : sWl;

  f32x4 acc[2][2];
#pragma unroll
  for (int i = 0; i < 2; ++i)
#pragma unroll
    for (int j = 0; j < 2; ++j) acc[i][j] = (f32x4)0.0f;

  for (int r3 = 0; r3 < 3; ++r3) {
    __syncthreads();
#pragma unroll
    for (int s = 0; s < 4; ++s)
#pragma unroll
      for (int slot = 0; slot < 4; ++slot)
        async16(gp[slot] + r3*128 + s*32, ldst + s*2048 + slot*512 + lane*8);
    __syncthreads();
#pragma unroll
    for (int s = 0; s < 4; ++s) {
      bf16x8 ah[2], al[2], bh[2], bl[2];
#pragma unroll
      for (int i = 0; i < 2; ++i) {
        int ro = s*2048 + (wr*32 + i*16 + t)*32 + pq;
        ah[i] = *(const bf16x8*)&sAh[ro];
        al[i] = *(const bf16x8*)&sAl[ro];
        int co = s*2048 + (wc*32 + i*16 + t)*32 + pq;
        bh[i] = *(const bf16x8*)&sWh[co];
        bl[i] = *(const bf16x8*)&sWl[co];
      }
#pragma unroll
      for (int i = 0; i < 2; ++i)
#pragma unroll
        for (int j = 0; j < 2; ++j) {
          acc[i][j] = __builtin_amdgcn_mfma_f32_16x16x32_bf16(ah[i], bh[j], acc[i][j], 0, 0, 0);
          acc[i][j] = __builtin_amdgcn_mfma_f32_16x16x32_bf16(ah[i], bl[j], acc[i][j], 0, 0, 0);
          acc[i][j] = __builtin_amdgcn_mfma_f32_16x16x32_bf16(al[i], bh[j], acc[i][j], 0, 0, 0);
        }
    }
  }

#pragma unroll
  for (int i = 0; i < 2; ++i)
#pragma unroll
    for (int j = 0; j < 2; ++j)
#pragma unroll
      for (int r = 0; r < 4; ++r) {
        int rloc = wr*32 + i*16 + quad*4 + r;
        int h = cbase + wc*32 + j*16 + t;
        float a = acc[i][j][r];
        if (xmode) {
          int g = blockIdx.x*64 + rloc;
          float v = a + b_ih[h];
          xp[(size_t)g*H + h] = v;
          int b = g / 6;
          if (g - b*6 == 0) {
            float hv = tanhf(v + b_hh[h]);
            ushort_t hi = f2bf(hv);
            hoh[(size_t)b*H + h] = hi;
            hol[(size_t)b*H + h] = f2bf(hv - bf2f(hi));
          }
        } else {
          int rq = (blockIdx.x - 96)*64 + rloc;
          gate[(size_t)rq*H + h] = 1.0f / (1.0f + expf(-(a + b_g[h])));
        }
      }
}

// ================= RNN step: h' = tanh(x_t + h @ W_hh^T + b_hh) =============
// grid (16, 6); LAST fuses the gated output blend
template<int LAST>
__global__ __launch_bounds__(256) void k_rnn(
    const ushort_t* __restrict__ hih, const ushort_t* __restrict__ hil,
    const ushort_t* __restrict__ whhh, const ushort_t* __restrict__ whhl,
    const float* __restrict__ b_hh, const float* __restrict__ xp,
    const float* __restrict__ gate, int step,
    ushort_t* __restrict__ hoh, ushort_t* __restrict__ hol,
    float* __restrict__ out) {
  __shared__ __align__(16) ushort_t sAh[64*128];
  __shared__ __align__(16) ushort_t sAl[64*128];
  __shared__ __align__(16) ushort_t sWh[64*128];
  __shared__ __align__(16) ushort_t sWl[64*128];

  const int tid = threadIdx.x, lane = tid & 63, wave = tid >> 6;
  const int wr = wave >> 1, wc = wave & 1;
  const int t = lane & 15, quad = lane >> 4;
  const int rbase = blockIdx.x * 64, cbase = blockIdx.y * 64;
  const int rowoff = lane >> 2, koff = swz_koff(lane);
  const int pq = (quad ^ ((t >> 1) & 3)) * 8;

  const ushort_t* gp[4];
#pragma unroll
  for (int slot = 0; slot < 4; ++slot) {
    int rl = slot*16 + rowoff;
    const ushort_t* src =
        (wave == 0) ? hih + (size_t)(rbase + rl)*D :
        (wave == 1) ? hil + (size_t)(rbase + rl)*D :
        (wave == 2) ? whhh + (size_t)(cbase + rl)*D :
                      whhl + (size_t)(cbase + rl)*D;
    gp[slot] = src + koff;
  }
  ushort_t* ldst = (wave == 0) ? sAh : (wave == 1) ? sAl : (wave == 2) ? sWh : sWl;

  f32x4 acc[2][2];
#pragma unroll
  for (int i = 0; i < 2; ++i)
#pragma unroll
    for (int j = 0; j < 2; ++j) acc[i][j] = (f32x4)0.0f;

  for (int r3 = 0; r3 < 3; ++r3) {
    __syncthreads();
#pragma unroll
    for (int s = 0; s < 4; ++s)
#pragma unroll
      for (int slot = 0; slot < 4; ++slot)
        async16(gp[slot] + r3*128 + s*32, ldst + s*2048 + slot*512 + lane*8);
    __syncthreads();
#pragma unroll
    for (int s = 0; s < 4; ++s) {
      bf16x8 ah[2], al[2], bh[2], bl[2];
#pragma unroll
      for (int i = 0; i < 2; ++i) {
        int ro = s*2048 + (wr*32 + i*16 + t)*32 + pq;
        ah[i] = *(const bf16x8*)&sAh[ro];
        al[i] = *(const bf16x8*)&sAl[ro];
        int co = s*2048 + (wc*32 + i*16 + t)*32 + pq;
        bh[i] = *(const bf16x8*)&sWh[co];
        bl[i] = *(const bf16x8*)&sWl[co];
      }
#pragma unroll
      for (int i = 0; i < 2; ++i)
#pragma unroll
        for (int j = 0; j < 2; ++j) {
          acc[i][j] = __builtin_amdgcn_mfma_f32_16x16x32_bf16(ah[i], bh[j], acc[i][j], 0, 0, 0);
          acc[i][j] = __builtin_amdgcn_mfma_f32_16x16x32_bf16(ah[i], bl[j], acc[i][j], 0, 0, 0);
          acc[i][j] = __builtin_amdgcn_mfma_f32_16x16x32_bf16(al[i], bh[j], acc[i][j], 0, 0, 0);
        }
    }
  }

#pragma unroll
  for (int i = 0; i < 2; ++i)
#pragma unroll
    for (int j = 0; j < 2; ++j)
#pragma unroll
      for (int r = 0; r < 4; ++r) {
        int row = rbase + wr*32 + i*16 + quad*4 + r;
        int h = cbase + wc*32 + j*16 + t;
        float v = acc[i][j][r] + b_hh[h] + xp[(size_t)row*(6*H) + step*H + h];
        float hv = tanhf(v);
        if (LAST) {
          float g = gate[(size_t)row*H + h];
          out[(size_t)row*H + h] = g*hv + (1.0f - g)*xp[(size_t)row*(6*H) + h];
        } else {
          ushort_t hi = f2bf(hv);
          hoh[(size_t)row*H + h] = hi;
          hol[(size_t)row*H + h] = f2bf(hv - bf2f(hi));
        }
      }
}

} // namespace

extern "C" void kernel_launch(void* const* d_in, const int* in_sizes, int n_in,
                              void* d_out, int out_size, void* d_ws, size_t ws_size,
                              hipStream_t stream) {
  const float* query = (const float*)d_in[0];
  const float* memv  = (const float*)d_in[1];
  const float* coords= (const float*)d_in[2];
  const float* sw    = (const float*)d_in[3];
  const float* W_ih  = (const float*)d_in[4];
  const float* b_ih  = (const float*)d_in[5];
  const float* W_hh  = (const float*)d_in[6];
  const float* b_hh  = (const float*)d_in[7];
  const float* W_g   = (const float*)d_in[8];
  const float* b_g   = (const float*)d_in[9];
  float* out = (float*)d_out;

  char* p = (char*)d_ws;
  auto alloc = [&](size_t bytes) {
    char* r = p; p += (bytes + 255) & ~(size_t)255; return r;
  };
  ushort_t* qh  = (ushort_t*)alloc((size_t)B * D * 2);
  ushort_t* qrh = (ushort_t*)alloc((size_t)B * D * 2);
  ushort_t* qrl = (ushort_t*)alloc((size_t)B * D * 2);
  ushort_t* mh  = (ushort_t*)alloc((size_t)M * D * 2);
  ushort_t* ml  = (ushort_t*)alloc((size_t)M * D * 2);
  float2* f2a   = (float2*)alloc((size_t)M * 8);
  float2* f2b   = (float2*)alloc((size_t)M * 8);
  ushort_t* wihh = (ushort_t*)alloc((size_t)H * D * 2);
  ushort_t* wihl = (ushort_t*)alloc((size_t)H * D * 2);
  ushort_t* whhh = (ushort_t*)alloc((size_t)H * D * 2);
  ushort_t* whhl = (ushort_t*)alloc((size_t)H * D * 2);
  ushort_t* wgh  = (ushort_t*)alloc((size_t)H * D * 2);
  ushort_t* wgl  = (ushort_t*)alloc((size_t)H * D * 2);
  unsigned int* keybuf = (unsigned int*)alloc((size_t)B * NC * 12 * 4);
  int*   topk   = (int*)alloc((size_t)B * KK * 4);
  float* xp     = (float*)alloc((size_t)B * 6 * H * 4);
  float* gate   = (float*)alloc((size_t)B * H * 4);
  ushort_t* hAh = (ushort_t*)alloc((size_t)B * H * 2);
  ushort_t* hAl = (ushort_t*)alloc((size_t)B * H * 2);
  ushort_t* hBh = (ushort_t*)alloc((size_t)B * H * 2);
  ushort_t* hBl = (ushort_t*)alloc((size_t)B * H * 2);

  k_prep<<<M/4 + B/4 + 288, 256, 0, stream>>>(
      query, memv, coords, sw, W_ih, W_hh, W_g,
      qh, qrh, qrl, mh, ml, f2a, f2b,
      wihh, wihl, whhh, whhl, wgh, wgl);
  k_sim<<<1024, 256, 0, stream>>>(qh, mh, f2a, keybuf);
  k_merge<<<B, 256, 0, stream>>>(keybuf, query, memv, f2b, topk);
  k_tail1<<<dim3(112, 6), 256, 0, stream>>>(
      qrh, qrl, mh, ml, topk, wihh, wihl, wgh, wgl,
      b_ih, b_hh, b_g, xp, gate, hAh, hAl);
  k_rnn<0><<<dim3(16, 6), 256, 0, stream>>>(hAh, hAl, whhh, whhl, b_hh, xp, gate, 1, hBh, hBl, out);
  k_rnn<0><<<dim3(16, 6), 256, 0, stream>>>(hBh, hBl, whhh, whhl, b_hh, xp, gate, 2, hAh, hAl, out);
  k_rnn<0><<<dim3(16, 6), 256, 0, stream>>>(hAh, hAl, whhh, whhl, b_hh, xp, gate, 3, hBh, hBl, out);
  k_rnn<0><<<dim3(16, 6), 256, 0, stream>>>(hBh, hBl, whhh, whhl, b_hh, xp, gate, 4, hAh, hAl, out);
  k_rnn<1><<<dim3(16, 6), 256, 0, stream>>>(hAh, hAl, whhh, whhl, b_hh, xp, gate, 5, hBh, hBl, out);
}

// Round 9
// 347.264 us; speedup vs baseline: 1.4840x; 1.0466x over previous
//
#include <hip/hip_runtime.h>
#include <math.h>

namespace {

typedef float f32x4 __attribute__((ext_vector_type(4)));
typedef float f32x16 __attribute__((ext_vector_type(16)));
typedef short bf16x8 __attribute__((ext_vector_type(8)));
typedef unsigned short ushort_t;

constexpr int B  = 1024;
constexpr int M  = 65536;
constexpr int D  = 384;
constexpr int H  = 384;
constexpr int KK = 5;
constexpr int NC = 128;         // chunks over M
constexpr int CHUNK = M / NC;   // 512 mems per chunk
constexpr float FEPS = 1e-8f;

__device__ __forceinline__ ushort_t f2bf(float x) {
  unsigned int u = __float_as_uint(x);
  unsigned int r = (u + 0x7FFFu + ((u >> 16) & 1u)) >> 16;   // RNE
  return (ushort_t)r;
}
__device__ __forceinline__ float bf2f(ushort_t h) {
  return __uint_as_float(((unsigned int)h) << 16);
}

__device__ __forceinline__ void async16(const ushort_t* g, ushort_t* l) {
  __builtin_amdgcn_global_load_lds(
      (const __attribute__((address_space(1))) unsigned int*)g,
      (__attribute__((address_space(3))) unsigned int*)l, 16, 0, 0);
}

__device__ __forceinline__ void insert3b(unsigned int* k, unsigned int v) {
  unsigned int t0 = min(k[0], v); k[0] = max(k[0], v);
  unsigned int t1 = min(k[1], t0); k[1] = max(k[1], t0);
  k[2] = max(k[2], t1);
}
__device__ __forceinline__ void insert5b(unsigned int* k, unsigned int v) {
  unsigned int t0 = min(k[0], v); k[0] = max(k[0], v);
  unsigned int t1 = min(k[1], t0); k[1] = max(k[1], t0);
  unsigned int t2 = min(k[2], t1); k[2] = max(k[2], t1);
  unsigned int t3 = min(k[3], t2); k[3] = max(k[3], t2);
  k[4] = max(k[4], t3);
}

// swizzled per-lane global k-offset for staging: LDS granule (lane&3) of row
// (lane>>2) holds logical granule (lane&3) ^ ((row>>1)&3).  [bank-conflict fix]
__device__ __forceinline__ int swz_koff(int lane) {
  return (((lane & 3) ^ ((lane >> 3) & 3)) * 8);
}

// ======= prep: mem hi-split+stats | q norm-hi | weight hi/lo splits =========
__global__ __launch_bounds__(256) void k_prep(
    const float* __restrict__ q, const float* __restrict__ mem,
    const float* __restrict__ coords, const float* __restrict__ sw,
    const float* __restrict__ W_ih, const float* __restrict__ W_hh,
    const float* __restrict__ W_g,
    ushort_t* __restrict__ qh, ushort_t* __restrict__ mh,
    float2* __restrict__ f2a, float2* __restrict__ f2b,
    ushort_t* __restrict__ wihh, ushort_t* __restrict__ wihl,
    ushort_t* __restrict__ whhh, ushort_t* __restrict__ whhl,
    ushort_t* __restrict__ wgh, ushort_t* __restrict__ wgl) {
  int wv = threadIdx.x >> 6, lane = threadIdx.x & 63;
  int bid = blockIdx.x;
  if (bid < M/4) {
    int r = bid*4 + wv;
    float cx = 0.f, cy = 0.f;
    for (int i = lane; i < H; i += 64) { cx += sw[2*i]; cy += sw[2*i+1]; }
#pragma unroll
    for (int o = 32; o > 0; o >>= 1) { cx += __shfl_xor(cx, o); cy += __shfl_xor(cy, o); }
    cx *= (1.0f/384.0f); cy *= (1.0f/384.0f);
    float2 x[3]; float s = 0.f;
#pragma unroll
    for (int k = 0; k < 3; ++k) {
      x[k] = ((const float2*)(mem + (size_t)r*D))[lane + 64*k];
      s += x[k].x*x[k].x + x[k].y*x[k].y;
    }
#pragma unroll
    for (int o = 32; o > 0; o >>= 1) s += __shfl_xor(s, o);
#pragma unroll
    for (int k = 0; k < 3; ++k) {
      ushort2 hh; hh.x = f2bf(x[k].x); hh.y = f2bf(x[k].y);
      ((ushort2*)(mh + (size_t)r*D))[lane + 64*k] = hh;
    }
    if (lane == 0) {
      float mn = sqrtf(s);
      float dx = coords[2*r] - cx, dy = coords[2*r+1] - cy;
      float act = 1.0f / (1.0f + sqrtf(dx*dx + dy*dy));
      f2a[r] = make_float2(1.0f / mn, act + 2.0f);
      f2b[r] = make_float2(mn, act);
    }
  } else if (bid < M/4 + B/4) {
    int r = (bid - M/4)*4 + wv;
    float2 x[3]; float s = 0.f;
#pragma unroll
    for (int k = 0; k < 3; ++k) {
      x[k] = ((const float2*)(q + (size_t)r*D))[lane + 64*k];
      s += x[k].x*x[k].x + x[k].y*x[k].y;
    }
#pragma unroll
    for (int o = 32; o > 0; o >>= 1) s += __shfl_xor(s, o);
    float inv = 1.0f / sqrtf(s);
#pragma unroll
    for (int k = 0; k < 3; ++k) {
      ushort2 nn; nn.x = f2bf(x[k].x * inv); nn.y = f2bf(x[k].y * inv);
      ((ushort2*)(qh + (size_t)r*D))[lane + 64*k] = nn;
    }
  } else {
    int r = (bid - M/4 - B/4)*4 + wv;   // 0..1151
    const float* src; ushort_t* dh; ushort_t* dl;
    if (r < 384)      { src = W_ih + (size_t)r*D;       dh = wihh + (size_t)r*D;       dl = wihl + (size_t)r*D; }
    else if (r < 768) { src = W_hh + (size_t)(r-384)*D; dh = whhh + (size_t)(r-384)*D; dl = whhl + (size_t)(r-384)*D; }
    else              { src = W_g  + (size_t)(r-768)*D; dh = wgh  + (size_t)(r-768)*D; dl = wgl  + (size_t)(r-768)*D; }
#pragma unroll
    for (int k = 0; k < 3; ++k) {
      float2 v = ((const float2*)src)[lane + 64*k];
      ushort_t h0 = f2bf(v.x), h1 = f2bf(v.y);
      ushort2 hh; hh.x = h0; hh.y = h1;
      ushort2 ll; ll.x = f2bf(v.x - bf2f(h0)); ll.y = f2bf(v.y - bf2f(h1));
      ((ushort2*)dh)[lane + 64*k] = hh;
      ((ushort2*)dl)[lane + 64*k] = ll;
    }
  }
}

// ====== sim: 1-term mh x qh 32x32x16 MFMA, BK=64, 2 LDS arrays ======
// 1D grid 1024; XCD-aware decode: the 8 q-tiles sharing chunk nc are
// consecutive on XCD nc%8 -> chunk read from HBM once, L2-hit 7x.
// BK=64 staged as two 32-col sub-blocks (R7 pattern) -> half the barriers.
__global__ __launch_bounds__(256, 2) void k_sim(
    const ushort_t* __restrict__ qh,
    const ushort_t* __restrict__ mh,
    const float2* __restrict__ f2a, unsigned int* __restrict__ keybuf) {
  __shared__ __align__(16) ushort_t sQh[2*4096];
  __shared__ __align__(16) ushort_t sMh[2*4096];
  __shared__ __align__(16) float2 sF[CHUNK];   // per-chunk (1/mn, act+2)

  const int tid = threadIdx.x, lane = tid & 63, wave = tid >> 6;
  const int wr = wave >> 1, wc = wave & 1;
  const int l31 = lane & 31, half = lane >> 5;
  const int flat = blockIdx.x;
  const int k8 = flat & 7, qb = (flat >> 3) & 7, mgrp = flat >> 6;
  const int nc = (mgrp << 3) | k8;
  const int rowoff = lane >> 2, koff = swz_koff(lane);
  const int gsw = (l31 >> 1) & 3;          // read-side swizzle
  const size_t qrow0 = (size_t)qb * 128;

  // stage chunk stats once (coalesced): 256 x float4 = 512 float2
  ((float4*)sF)[tid] = ((const float4*)(f2a + (size_t)nc * CHUNK))[tid];

  unsigned int keys[2][3];
#pragma unroll
  for (int j = 0; j < 2; ++j) { keys[j][0] = 0; keys[j][1] = 0; keys[j][2] = 0; }

  for (int mt = 0; mt < 4; ++mt) {
    const size_t mrow0 = (size_t)nc * CHUNK + (size_t)mt * 128;
    f32x16 acc[2][2];
#pragma unroll
    for (int i = 0; i < 2; ++i)
#pragma unroll
      for (int j = 0; j < 2; ++j) acc[i][j] = (f32x16)0.0f;

    for (int kt = 0; kt < D; kt += 64) {
      __syncthreads();
      // 32 async16 stages across 4 waves: arr(2) x kb(2) x slot(8)
#pragma unroll
      for (int n = 0; n < 8; ++n) {
        int f = wave*8 + n;
        int arr = f >> 4, sub = f & 15, kb = sub >> 3, slot = sub & 7;
        const ushort_t* src = arr == 0 ? qh : mh;
        ushort_t* dst = arr == 0 ? sQh : sMh;
        size_t rowb = arr == 0 ? qrow0 : mrow0;
        async16(src + (rowb + slot*16 + rowoff)*D + kt + kb*32 + koff,
                dst + kb*4096 + slot*512 + lane*8);
      }
      __syncthreads();

#pragma unroll
      for (int kb = 0; kb < 2; ++kb) {
        const int base = kb*4096;
        bf16x8 ah[2][2], bh[2][2];
#pragma unroll
        for (int i = 0; i < 2; ++i)
#pragma unroll
          for (int s = 0; s < 2; ++s) {
            int gra = ((s*2 + half) ^ gsw) * 8;
            int ro = base + (wr*64 + i*32 + l31)*32 + gra;
            ah[i][s] = *(const bf16x8*)&sMh[ro];
            int co = base + (wc*64 + i*32 + l31)*32 + gra;
            bh[i][s] = *(const bf16x8*)&sQh[co];
          }
#pragma unroll
        for (int i = 0; i < 2; ++i)
#pragma unroll
          for (int j = 0; j < 2; ++j)
#pragma unroll
            for (int s = 0; s < 2; ++s)
              acc[i][j] = __builtin_amdgcn_mfma_f32_32x32x16_bf16(ah[i][s], bh[j][s], acc[i][j], 0, 0, 0);
      }
    }

    // epilogue: C layout col=lane&31, row=(r&3)+8*(r>>2)+4*half; stats from LDS
#pragma unroll
    for (int i = 0; i < 2; ++i)
#pragma unroll
      for (int rg = 0; rg < 4; ++rg)
#pragma unroll
        for (int rr = 0; rr < 4; ++rr) {
          int rl = wr*64 + i*32 + half*4 + rr + 8*rg;
          float2 fa = sF[mt*128 + rl];
          unsigned int idx = (unsigned int)(((nc & 1) << 9) | (mt*128 + rl));
          float v0 = fmaf(acc[i][0][rg*4+rr], fa.x, fa.y);
          insert3b(keys[0], (__float_as_uint(v0) & 0xFFFFFC00u) | idx);
          float v1 = fmaf(acc[i][1][rg*4+rr], fa.x, fa.y);
          insert3b(keys[1], (__float_as_uint(v1) & 0xFFFFFC00u) | idx);
        }
  }

#pragma unroll
  for (int j = 0; j < 2; ++j) {
    int q_local = wc*64 + j*32 + l31;
    int c = wr*2 + half;
    size_t off = ((size_t)(qb*128 + q_local) * NC + nc) * 12 + c*3;
    keybuf[off+0] = keys[j][0];
    keybuf[off+1] = keys[j][1];
    keybuf[off+2] = keys[j][2];
  }
}

// == merge: block/query; tournament + exact rescore + fused seq gather-split ==
__global__ __launch_bounds__(256) void k_merge(
    const unsigned int* __restrict__ keybuf,
    const float* __restrict__ query, const float* __restrict__ memv,
    const float2* __restrict__ f2b,
    ushort_t* __restrict__ xsh, ushort_t* __restrict__ xsl) {
  __shared__ int sCand[16];
  __shared__ float sSimv[16];
  __shared__ int sTop[KK];
  const int tid = threadIdx.x, lane = tid & 63, wave = tid >> 6;
  const int q = blockIdx.x;

  if (wave == 0) {
    // lane covers chunks 2*lane, 2*lane+1: 24 contiguous keys
    const unsigned int* kb = keybuf + (size_t)q * (NC*12) + (size_t)lane * 24;
    unsigned int k5[5] = {0,0,0,0,0};
#pragma unroll
    for (int c = 0; c < 6; ++c) {
      uint4 v = *(const uint4*)(kb + c*4);
      insert5b(k5, v.x); insert5b(k5, v.y); insert5b(k5, v.z); insert5b(k5, v.w);
    }
#pragma unroll
    for (int p = 0; p < 16; ++p) {
      unsigned int bk = k5[0]; int blv = lane;
#pragma unroll
      for (int off = 1; off < 64; off <<= 1) {
        unsigned int ok = (unsigned int)__shfl_xor((int)bk, off);
        int ol = __shfl_xor(blv, off);
        if (ok > bk || (ok == bk && ol < blv)) { bk = ok; blv = ol; }
      }
      if (lane == blv) { k5[0]=k5[1]; k5[1]=k5[2]; k5[2]=k5[3]; k5[3]=k5[4]; k5[4]=0; }
      if (lane == 0) sCand[p] = (blv << 10) | (int)(bk & 1023u);
    }
  }
  __syncthreads();

  // each wave rescores 4 candidates in exact fp32
  float qv[6]; float sq = 0.f;
#pragma unroll
  for (int k = 0; k < 6; ++k) { qv[k] = query[(size_t)q*D + lane + 64*k]; sq += qv[k]*qv[k]; }
#pragma unroll
  for (int o = 32; o > 0; o >>= 1) sq += __shfl_xor(sq, o);
  float qn = sqrtf(sq);

#pragma unroll
  for (int pp = 0; pp < 4; ++pp) {
    int p = wave*4 + pp;
    int mi = sCand[p];
    float d = 0.f;
#pragma unroll
    for (int k = 0; k < 6; ++k) d += qv[k] * memv[(size_t)mi*D + lane + 64*k];
#pragma unroll
    for (int o = 32; o > 0; o >>= 1) d += __shfl_xor(d, o);
    if (lane == 0) {
      float2 fb = f2b[mi];
      sSimv[p] = d / fmaxf(qn * fb.x, FEPS) + fb.y;
    }
  }
  __syncthreads();

  if (tid == 0) {
    float cv[16]; int ci[16];
#pragma unroll
    for (int p = 0; p < 16; ++p) { cv[p] = sSimv[p]; ci[p] = sCand[p]; }
    for (int s = 0; s < KK; ++s) {
      int best = -1; float bv = -1e30f; int bi = 0x7FFFFFFF;
      for (int p = 0; p < 16; ++p) {
        if (ci[p] < 0) continue;
        if (cv[p] > bv || (cv[p] == bv && ci[p] < bi)) { best = p; bv = cv[p]; bi = ci[p]; }
      }
      sTop[s] = ci[best];
      ci[best] = -1;
    }
  }
  __syncthreads();

  // fused seq gather + hi/lo split: rows g = q*6 + t (t=0 query, t>0 retrieved)
#pragma unroll
  for (int rep = 0; rep < 2; ++rep) {
    int t = wave + rep*4;
    if (t < 6) {
      const float* src = (t == 0) ? (query + (size_t)q*D)
                                  : (memv + (size_t)sTop[t-1]*D);
      size_t g = (size_t)q*6 + t;
#pragma unroll
      for (int k = 0; k < 3; ++k) {
        float2 v = ((const float2*)src)[lane + 64*k];
        ushort_t h0 = f2bf(v.x), h1 = f2bf(v.y);
        ushort2 hh; hh.x = h0; hh.y = h1;
        ushort2 ll; ll.x = f2bf(v.x - bf2f(h0)); ll.y = f2bf(v.y - bf2f(h1));
        ((ushort2*)(xsh + g*D))[lane + 64*k] = hh;
        ((ushort2*)(xsl + g*D))[lane + 64*k] = ll;
      }
    }
  }
}

// ===== tail1: x_proj (contiguous seq rows, 96 tiles) + gate (16 tiles) + h1 =
// grid (112, 6); 64x64 tile, K=384 in 3 rounds of 4x32 subtiles; 3-term split
__global__ __launch_bounds__(256) void k_tail1(
    const ushort_t* __restrict__ xsh, const ushort_t* __restrict__ xsl,
    const ushort_t* __restrict__ wihh, const ushort_t* __restrict__ wihl,
    const ushort_t* __restrict__ wgh, const ushort_t* __restrict__ wgl,
    const float* __restrict__ b_ih, const float* __restrict__ b_hh,
    const float* __restrict__ b_g,
    float* __restrict__ xp, float* __restrict__ gate,
    ushort_t* __restrict__ hoh, ushort_t* __restrict__ hol) {
  __shared__ __align__(16) ushort_t sAh[64*128];
  __shared__ __align__(16) ushort_t sAl[64*128];
  __shared__ __align__(16) ushort_t sWh[64*128];
  __shared__ __align__(16) ushort_t sWl[64*128];

  const int tid = threadIdx.x, lane = tid & 63, wave = tid >> 6;
  const int wr = wave >> 1, wc = wave & 1;
  const int t = lane & 15, quad = lane >> 4;
  const bool xmode = blockIdx.x < 96;
  const int cbase = blockIdx.y * 64;
  const int rowoff = lane >> 2, koff = swz_koff(lane);
  const int pq = (quad ^ ((t >> 1) & 3)) * 8;    // swizzled read granule

  const ushort_t* gp[4];
  if (wave < 2) {
    const ushort_t* base = (wave == 0) ? xsh : xsl;
#pragma unroll
    for (int slot = 0; slot < 4; ++slot) {
      int rl = slot*16 + rowoff;
      size_t row = xmode ? (size_t)(blockIdx.x*64 + rl)
                         : (size_t)((blockIdx.x - 96)*64 + rl) * 6;
      gp[slot] = base + row*D + koff;
    }
  } else {
#pragma unroll
    for (int slot = 0; slot < 4; ++slot) {
      int rl = slot*16 + rowoff;
      const ushort_t* wsrc = xmode ? (wave == 2 ? wihh : wihl)
                                   : (wave == 2 ? wgh  : wgl);
      gp[slot] = wsrc + (size_t)(cbase + rl) * D + koff;
    }
  }
  ushort_t* ldst = (wave == 0) ? sAh : (wave == 1) ? sAl : (wave == 2) ? sWh : sWl;

  f32x4 acc[2][2];
#pragma unroll
  for (int i = 0; i < 2; ++i)
#pragma unroll
    for (int j = 0; j < 2; ++j) acc[i][j] = (f32x4)0.0f;

  for (int r3 = 0; r3 < 3; ++r3) {
    __syncthreads();
#pragma unroll
    for (int s = 0; s < 4; ++s)
#pragma unroll
      for (int slot = 0; slot < 4; ++slot)
        async16(gp[slot] + r3*128 + s*32, ldst + s*2048 + slot*512 + lane*8);
    __syncthreads();
#pragma unroll
    for (int s = 0; s < 4; ++s) {
      bf16x8 ah[2], al[2], bh[2], bl[2];
#pragma unroll
      for (int i = 0; i < 2; ++i) {
        int ro = s*2048 + (wr*32 + i*16 + t)*32 + pq;
        ah[i] = *(const bf16x8*)&sAh[ro];
        al[i] = *(const bf16x8*)&sAl[ro];
        int co = s*2048 + (wc*32 + i*16 + t)*32 + pq;
        bh[i] = *(const bf16x8*)&sWh[co];
        bl[i] = *(const bf16x8*)&sWl[co];
      }
#pragma unroll
      for (int i = 0; i < 2; ++i)
#pragma unroll
        for (int j = 0; j < 2; ++j) {
          acc[i][j] = __builtin_amdgcn_mfma_f32_16x16x32_bf16(ah[i], bh[j], acc[i][j], 0, 0, 0);
          acc[i][j] = __builtin_amdgcn_mfma_f32_16x16x32_bf16(ah[i], bl[j], acc[i][j], 0, 0, 0);
          acc[i][j] = __builtin_amdgcn_mfma_f32_16x16x32_bf16(al[i], bh[j], acc[i][j], 0, 0, 0);
        }
    }
  }

#pragma unroll
  for (int i = 0; i < 2; ++i)
#pragma unroll
    for (int j = 0; j < 2; ++j)
#pragma unroll
      for (int r = 0; r < 4; ++r) {
        int rloc = wr*32 + i*16 + quad*4 + r;
        int h = cbase + wc*32 + j*16 + t;
        float a = acc[i][j][r];
        if (xmode) {
          int g = blockIdx.x*64 + rloc;
          float v = a + b_ih[h];
          xp[(size_t)g*H + h] = v;
          int b = g / 6;
          if (g - b*6 == 0) {
            float hv = tanhf(v + b_hh[h]);
            ushort_t hi = f2bf(hv);
            hoh[(size_t)b*H + h] = hi;
            hol[(size_t)b*H + h] = f2bf(hv - bf2f(hi));
          }
        } else {
          int rq = (blockIdx.x - 96)*64 + rloc;
          gate[(size_t)rq*H + h] = 1.0f / (1.0f + expf(-(a + b_g[h])));
        }
      }
}

// ================= RNN step: h' = tanh(x_t + h @ W_hh^T + b_hh) =============
// grid (16, 6); LAST fuses the gated output blend
template<int LAST>
__global__ __launch_bounds__(256) void k_rnn(
    const ushort_t* __restrict__ hih, const ushort_t* __restrict__ hil,
    const ushort_t* __restrict__ whhh, const ushort_t* __restrict__ whhl,
    const float* __restrict__ b_hh, const float* __restrict__ xp,
    const float* __restrict__ gate, int step,
    ushort_t* __restrict__ hoh, ushort_t* __restrict__ hol,
    float* __restrict__ out) {
  __shared__ __align__(16) ushort_t sAh[64*128];
  __shared__ __align__(16) ushort_t sAl[64*128];
  __shared__ __align__(16) ushort_t sWh[64*128];
  __shared__ __align__(16) ushort_t sWl[64*128];

  const int tid = threadIdx.x, lane = tid & 63, wave = tid >> 6;
  const int wr = wave >> 1, wc = wave & 1;
  const int t = lane & 15, quad = lane >> 4;
  const int rbase = blockIdx.x * 64, cbase = blockIdx.y * 64;
  const int rowoff = lane >> 2, koff = swz_koff(lane);
  const int pq = (quad ^ ((t >> 1) & 3)) * 8;

  const ushort_t* gp[4];
#pragma unroll
  for (int slot = 0; slot < 4; ++slot) {
    int rl = slot*16 + rowoff;
    const ushort_t* src =
        (wave == 0) ? hih + (size_t)(rbase + rl)*D :
        (wave == 1) ? hil + (size_t)(rbase + rl)*D :
        (wave == 2) ? whhh + (size_t)(cbase + rl)*D :
                      whhl + (size_t)(cbase + rl)*D;
    gp[slot] = src + koff;
  }
  ushort_t* ldst = (wave == 0) ? sAh : (wave == 1) ? sAl : (wave == 2) ? sWh : sWl;

  f32x4 acc[2][2];
#pragma unroll
  for (int i = 0; i < 2; ++i)
#pragma unroll
    for (int j = 0; j < 2; ++j) acc[i][j] = (f32x4)0.0f;

  for (int r3 = 0; r3 < 3; ++r3) {
    __syncthreads();
#pragma unroll
    for (int s = 0; s < 4; ++s)
#pragma unroll
      for (int slot = 0; slot < 4; ++slot)
        async16(gp[slot] + r3*128 + s*32, ldst + s*2048 + slot*512 + lane*8);
    __syncthreads();
#pragma unroll
    for (int s = 0; s < 4; ++s) {
      bf16x8 ah[2], al[2], bh[2], bl[2];
#pragma unroll
      for (int i = 0; i < 2; ++i) {
        int ro = s*2048 + (wr*32 + i*16 + t)*32 + pq;
        ah[i] = *(const bf16x8*)&sAh[ro];
        al[i] = *(const bf16x8*)&sAl[ro];
        int co = s*2048 + (wc*32 + i*16 + t)*32 + pq;
        bh[i] = *(const bf16x8*)&sWh[co];
        bl[i] = *(const bf16x8*)&sWl[co];
      }
#pragma unroll
      for (int i = 0; i < 2; ++i)
#pragma unroll
        for (int j = 0; j < 2; ++j) {
          acc[i][j] = __builtin_amdgcn_mfma_f32_16x16x32_bf16(ah[i], bh[j], acc[i][j], 0, 0, 0);
          acc[i][j] = __builtin_amdgcn_mfma_f32_16x16x32_bf16(ah[i], bl[j], acc[i][j], 0, 0, 0);
          acc[i][j] = __builtin_amdgcn_mfma_f32_16x16x32_bf16(al[i], bh[j], acc[i][j], 0, 0, 0);
        }
    }
  }

#pragma unroll
  for (int i = 0; i < 2; ++i)
#pragma unroll
    for (int j = 0; j < 2; ++j)
#pragma unroll
      for (int r = 0; r < 4; ++r) {
        int row = rbase + wr*32 + i*16 + quad*4 + r;
        int h = cbase + wc*32 + j*16 + t;
        float v = acc[i][j][r] + b_hh[h] + xp[(size_t)row*(6*H) + step*H + h];
        float hv = tanhf(v);
        if (LAST) {
          float g = gate[(size_t)row*H + h];
          out[(size_t)row*H + h] = g*hv + (1.0f - g)*xp[(size_t)row*(6*H) + h];
        } else {
          ushort_t hi = f2bf(hv);
          hoh[(size_t)row*H + h] = hi;
          hol[(size_t)row*H + h] = f2bf(hv - bf2f(hi));
        }
      }
}

} // namespace

extern "C" void kernel_launch(void* const* d_in, const int* in_sizes, int n_in,
                              void* d_out, int out_size, void* d_ws, size_t ws_size,
                              hipStream_t stream) {
  const float* query = (const float*)d_in[0];
  const float* memv  = (const float*)d_in[1];
  const float* coords= (const float*)d_in[2];
  const float* sw    = (const float*)d_in[3];
  const float* W_ih  = (const float*)d_in[4];
  const float* b_ih  = (const float*)d_in[5];
  const float* W_hh  = (const float*)d_in[6];
  const float* b_hh  = (const float*)d_in[7];
  const float* W_g   = (const float*)d_in[8];
  const float* b_g   = (const float*)d_in[9];
  float* out = (float*)d_out;

  char* p = (char*)d_ws;
  auto alloc = [&](size_t bytes) {
    char* r = p; p += (bytes + 255) & ~(size_t)255; return r;
  };
  ushort_t* qh  = (ushort_t*)alloc((size_t)B * D * 2);
  ushort_t* mh  = (ushort_t*)alloc((size_t)M * D * 2);
  float2* f2a   = (float2*)alloc((size_t)M * 8);
  float2* f2b   = (float2*)alloc((size_t)M * 8);
  ushort_t* wihh = (ushort_t*)alloc((size_t)H * D * 2);
  ushort_t* wihl = (ushort_t*)alloc((size_t)H * D * 2);
  ushort_t* whhh = (ushort_t*)alloc((size_t)H * D * 2);
  ushort_t* whhl = (ushort_t*)alloc((size_t)H * D * 2);
  ushort_t* wgh  = (ushort_t*)alloc((size_t)H * D * 2);
  ushort_t* wgl  = (ushort_t*)alloc((size_t)H * D * 2);
  unsigned int* keybuf = (unsigned int*)alloc((size_t)B * NC * 12 * 4);
  ushort_t* xsh = (ushort_t*)alloc((size_t)B * 6 * D * 2);
  ushort_t* xsl = (ushort_t*)alloc((size_t)B * 6 * D * 2);
  float* xp     = (float*)alloc((size_t)B * 6 * H * 4);
  float* gate   = (float*)alloc((size_t)B * H * 4);
  ushort_t* hAh = (ushort_t*)alloc((size_t)B * H * 2);
  ushort_t* hAl = (ushort_t*)alloc((size_t)B * H * 2);
  ushort_t* hBh = (ushort_t*)alloc((size_t)B * H * 2);
  ushort_t* hBl = (ushort_t*)alloc((size_t)B * H * 2);

  k_prep<<<M/4 + B/4 + 288, 256, 0, stream>>>(
      query, memv, coords, sw, W_ih, W_hh, W_g,
      qh, mh, f2a, f2b,
      wihh, wihl, whhh, whhl, wgh, wgl);
  k_sim<<<1024, 256, 0, stream>>>(qh, mh, f2a, keybuf);
  k_merge<<<B, 256, 0, stream>>>(keybuf, query, memv, f2b, xsh, xsl);
  k_tail1<<<dim3(112, 6), 256, 0, stream>>>(
      xsh, xsl, wihh, wihl, wgh, wgl,
      b_ih, b_hh, b_g, xp, gate, hAh, hAl);
  k_rnn<0><<<dim3(16, 6), 256, 0, stream>>>(hAh, hAl, whhh, whhl, b_hh, xp, gate, 1, hBh, hBl, out);
  k_rnn<0><<<dim3(16, 6), 256, 0, stream>>>(hBh, hBl, whhh, whhl, b_hh, xp, gate, 2, hAh, hAl, out);
  k_rnn<0><<<dim3(16, 6), 256, 0, stream>>>(hAh, hAl, whhh, whhl, b_hh, xp, gate, 3, hBh, hBl, out);
  k_rnn<0><<<dim3(16, 6), 256, 0, stream>>>(hBh, hBl, whhh, whhl, b_hh, xp, gate, 4, hAh, hAl, out);
  k_rnn<1><<<dim3(16, 6), 256, 0, stream>>>(hAh, hAl, whhh, whhl, b_hh, xp, gate, 5, hBh, hBl, out);
}